// Round 7
// baseline (87043.713 us; speedup 1.0000x reference)
//
#include <hip/hip_runtime.h>
#include <cmath>

#define NN 1024
#define DD 1024
#define BB 8
#define LL 4
#define OUTD (DD*(LL+1))   // 5120
#define NB 32
#define NPAN 32
#define BSTR ((size_t)NN*OUTD)
#define VSTR 540672ull     // per-batch ws floats for full-V dump

typedef short b8v __attribute__((ext_vector_type(8)));
typedef short s4v __attribute__((ext_vector_type(4)));
typedef float f4v __attribute__((ext_vector_type(4)));
typedef float f4  __attribute__((ext_vector_type(4)));

// group-XOR swizzle: permutes 8-row groups per column; k-order inside a group
// preserved, so b128 fragment reads stay contiguous+aligned and MFMA k-order
// matches between A and B operands (indexed by logical k on both sides).
#define SWZ(rowv,cv) (((((rowv)>>3)^(((cv)>>2)&7))<<3)|((rowv)&7))

__device__ __forceinline__ unsigned short f2bf(float x){
  unsigned u=__float_as_uint(x);
  return (unsigned short)((u + 0x7FFFu + ((u>>16)&1u))>>16);
}
__device__ __forceinline__ float bf2f(unsigned short h){
  return __uint_as_float(((unsigned)h)<<16);
}
// 3-split: x = h + m + l -> 6-product MFMA == fp32-equivalent (validated r5/r6)
__device__ __forceinline__ void bsplit3(float x, short& h, short& m, short& l){
  unsigned short hh=f2bf(x);
  float r1=x-bf2f(hh);
  unsigned short mm=f2bf(r1);
  float r2=r1-bf2f(mm);
  h=(short)hh; m=(short)mm; l=(short)f2bf(r2);
}
__device__ __forceinline__ f4v mfma6(b8v ah,b8v am,b8v al,b8v bh,b8v bm,b8v bl,f4v acc){
  acc=__builtin_amdgcn_mfma_f32_16x16x32_bf16(al,bh,acc,0,0,0);
  acc=__builtin_amdgcn_mfma_f32_16x16x32_bf16(ah,bl,acc,0,0,0);
  acc=__builtin_amdgcn_mfma_f32_16x16x32_bf16(am,bm,acc,0,0,0);
  acc=__builtin_amdgcn_mfma_f32_16x16x32_bf16(am,bh,acc,0,0,0);
  acc=__builtin_amdgcn_mfma_f32_16x16x32_bf16(ah,bm,acc,0,0,0);
  acc=__builtin_amdgcn_mfma_f32_16x16x32_bf16(ah,bh,acc,0,0,0);
  return acc;
}

// ---------------- setup ----------------
__global__ void k_deg_init(float* degF){ degF[threadIdx.x]=0.f; }

__global__ void k_deg(const int* __restrict__ ei, float* __restrict__ degF, int E){
  int e=blockIdx.x*blockDim.x+threadIdx.x;
  if(e<E) atomicAdd(&degF[ei[2*e]],1.f);
}

__global__ void k_scan(const float* __restrict__ degF, float* __restrict__ isq, int* __restrict__ rowoff){
  __shared__ int s[NN];
  int i=threadIdx.x;
  int d=(int)degF[i];
  s[i]=d; __syncthreads();
  for(int off=1;off<NN;off<<=1){
    int v=(i>=off)?s[i-off]:0;
    __syncthreads();
    s[i]+=v;
    __syncthreads();
  }
  if(i==0) rowoff[0]=0;
  rowoff[i+1]=s[i];
  isq[i]=(d>0)?(float)(1.0/sqrt((double)d)):0.f;
}

__global__ void k_copyx0(const float* __restrict__ x0, float* __restrict__ out){
  size_t t=(size_t)blockIdx.x*blockDim.x+threadIdx.x;
  if(t>=(size_t)BB*NN*DD) return;
  int d=(int)(t&(DD-1)); size_t bn=t>>10;
  out[bn*OUTD+d]=x0[t];
}

// ---------------- graph conv ----------------
__global__ void k_conv(const float* __restrict__ xin, const int* __restrict__ ei,
                       const float* __restrict__ degF, const float* __restrict__ isq,
                       const int* __restrict__ rowoff, float* Aout){
  int i=blockIdx.x, b=blockIdx.y;
  __shared__ int sdst[64]; __shared__ float sw[64];
  int r0=rowoff[i], r1=rowoff[i+1];
  int cnt=r1-r0; if(cnt>64) cnt=64;
  float di=degF[i], isqi=isq[i];
  for(int e=threadIdx.x;e<cnt;e+=blockDim.x){
    int dv=ei[2*(r0+e)+1];
    sdst[e]=dv; sw[e]=isqi*isq[dv];
  }
  __syncthreads();
  float cm=((float)(r1-r0))*di/fmaxf(di,1.f);
  const float* xi=xin+((size_t)(b*NN+i))*OUTD;
  float* ao=Aout+((size_t)(b*NN+i))*OUTD;
  for(int d=threadIdx.x; d<DD; d+=blockDim.x){
    float acc=0.f;
    for(int e=0;e<cnt;e++) acc+=sw[e]*xin[((size_t)(b*NN+sdst[e]))*OUTD+d];
    ao[d]=0.5f*acc+0.5f*cm*xi[d];
  }
}

// ---------------- in-register Householder panel factor (512 threads) -------
__device__ void panel_factor(float* p, int mq, float* vfslot, float* Twslot, char* SM){
  float (*Tsh)[33]=(float(*)[33])(SM);
  float* vsh =(float*)(SM+16896);
  float* red =(float*)(SM+20992);
  float* s_sh=(float*)(SM+23104);
  float* taus=(float*)(SM+23232);
  float* meta=(float*)(SM+23360);
  int tid=threadIdx.x, c=tid&31, rg=tid>>5;
  for(int idx=tid; idx<32*33; idx+=512) ((float*)Tsh)[idx]=0.f;
  __syncthreads();
  #pragma unroll 1
  for(int j=0;j<NB;j++){
    if(c==j){
      float ss=0.f;
      #pragma unroll
      for(int q=0;q<64;q++){ if(q>=mq) break;
        int r=rg+(q<<4);
        if(r>j) ss+=p[q]*p[q];
        else if(r==j) meta[2]=p[q];
      }
      red[rg*33+32]=ss;
    }
    __syncthreads();                                   // B1
    if(tid<16){
      float v=red[tid*33+32];
      #pragma unroll
      for(int o=8;o>0;o>>=1) v+=__shfl_xor(v,o,16);
      if(tid==0){
        float alpha=meta[2], ssq=v, tau, scale;
        if(ssq==0.f){tau=0.f;scale=0.f;}
        else{
          double bn=sqrt((double)alpha*(double)alpha+(double)ssq);
          float beta=(alpha>=0.f)?(float)(-bn):(float)bn; // -sign(alpha)*norm
          tau=(beta-alpha)/beta; scale=1.f/(alpha-beta);
        }
        taus[j]=tau; meta[0]=scale;
      }
    }
    __syncthreads();                                   // B2
    float tau=taus[j], scale=meta[0];
    if(c==j){
      #pragma unroll
      for(int q=0;q<64;q++){ if(q>=mq) break;
        int r=rg+(q<<4);
        if(r>j){p[q]*=scale; vsh[r]=p[q];}
        else if(r==j) vsh[r]=1.f;
      }
    }
    __syncthreads();                                   // B3
    {
      float acc=0.f;
      #pragma unroll
      for(int q=0;q<64;q++){ if(q>=mq) break;
        int r=rg+(q<<4);
        if(r>=j) acc+=vsh[r]*p[q];
      }
      red[rg*33+c]=acc;
    }
    __syncthreads();                                   // B4
    {
      int c2=tid>>4, q2=tid&15;
      float v=red[q2*33+c2];
      #pragma unroll
      for(int o=8;o>0;o>>=1) v+=__shfl_xor(v,o,16);
      if(q2==0) s_sh[c2]=v;
    }
    __syncthreads();                                   // B5
    if(c>j){
      float wv=tau*s_sh[c];
      #pragma unroll
      for(int q=0;q<64;q++){ if(q>=mq) break;
        int r=rg+(q<<4);
        if(r>=j) p[q]-=wv*vsh[r];
      }
    }
    if(tid<j){
      float s=0.f;
      for(int q2=tid;q2<j;q2++) s+=Tsh[tid][q2]*s_sh[q2];
      Tsh[tid][j]=-tau*s;
    } else if(tid==j) Tsh[j][j]=tau;
  }
  __syncthreads();
  #pragma unroll
  for(int q=0;q<64;q++){ if(q>=mq) break;
    int r=rg+(q<<4);
    vfslot[(size_t)r*32+c]=(r>c)?p[q]:((r==c)?1.f:0.f);
  }
  for(int idx=tid; idx<1024; idx+=512) Twslot[idx]=Tsh[idx>>5][idx&31];
}

// ---------------- block reflector apply, prefetched float4 staging ----------
// TRANS=true : cols <- (I - V T^T V^T) cols   (geqrf)
// TRANS=false: cols <- (I - V T   V^T) cols   (orgqr)
template<bool TRANS>
__device__ void blk_update(float* Ab, const float* __restrict__ vf, const float* __restrict__ Tb,
                           int k0, int c0, char* SM){
  float (*Tsh)[33]=(float(*)[33])(SM);              // 4224
  float (*Wt)[33] =(float(*)[33])(SM+4224);         // 4224
  float (*Wp)[32][33]=(float(*)[32][33])(SM+8448);  // 8448
  short (*W2h)[40]=(short(*)[40])(SM+8448);         // aliases Wp (dead by then)
  short (*W2m)[40]=(short(*)[40])(SM+11008);
  short (*W2l)[40]=(short(*)[40])(SM+13568);
  short (*VTh)[72]=(short(*)[72])(SM+16896);
  short (*VTm)[72]=(short(*)[72])(SM+21504);
  short (*VTl)[72]=(short(*)[72])(SM+26112);
  short (*STh)[72]=(short(*)[72])(SM+30720);
  short (*STm)[72]=(short(*)[72])(SM+35328);
  short (*STl)[72]=(short(*)[72])(SM+39936);        // -> 44544
  short (*V2h)[40]=(short(*)[40])(SM+16896);        // pass2 aliases
  short (*V2m)[40]=(short(*)[40])(SM+22016);
  short (*V2l)[40]=(short(*)[40])(SM+27136);
  int tid=threadIdx.x, w=tid>>6, lane=tid&63, lr=lane&15, lq=lane>>4;
  int m=NN-k0;
  for(int idx=tid; idx<1024; idx+=512) Tsh[idx>>5][idx&31]=Tb[idx];
  int row=tid>>3, c4=(tid&7)*4;
  const f4 fz={0.f,0.f,0.f,0.f};
  // ---- pass 1: W = V^T * stripe (K=m), prefetched double-issue ----
  f4 sP,vP,sN,vN;
  { int r=row;
    sP=(r<m)? *(const f4*)&Ab[(size_t)(k0+r)*OUTD+c0+c4] : fz;
    vP=(r<m)? *(const f4*)&vf[((size_t)r<<5)+c4] : fz; }
  int jt=w&1, ct=(w>>1)&1, kh=w>>2;
  f4v acc={0.f,0.f,0.f,0.f};
  int nt=(m+63)>>6;
  for(int t=0;t<nt;t++){
    short h,mi,lo;
    #pragma unroll
    for(int i=0;i<4;i++){
      int sl=SWZ(row,c4+i);
      bsplit3(vP[i],h,mi,lo);
      VTh[c4+i][sl]=h; VTm[c4+i][sl]=mi; VTl[c4+i][sl]=lo;
      bsplit3(sP[i],h,mi,lo);
      STh[c4+i][sl]=h; STm[c4+i][sl]=mi; STl[c4+i][sl]=lo;
    }
    if(t+1<nt){ int r=(t+1)*64+row;
      sN=(r<m)? *(const f4*)&Ab[(size_t)(k0+r)*OUTD+c0+c4] : fz;
      vN=(r<m)? *(const f4*)&vf[((size_t)r<<5)+c4] : fz;
    }
    __syncthreads();
    int g=kh*4+lq;
    int ja=jt*16+lr, cb=ct*16+lr;
    int koa=((g^((ja>>2)&7))<<3), kob=((g^((cb>>2)&7))<<3);
    b8v ah=*(const b8v*)&VTh[ja][koa];
    b8v am=*(const b8v*)&VTm[ja][koa];
    b8v al=*(const b8v*)&VTl[ja][koa];
    b8v bh=*(const b8v*)&STh[cb][kob];
    b8v bm=*(const b8v*)&STm[cb][kob];
    b8v bl=*(const b8v*)&STl[cb][kob];
    acc=mfma6(ah,am,al,bh,bm,bl,acc);
    __syncthreads();
    sP=sN; vP=vN;
  }
  #pragma unroll
  for(int i=0;i<4;i++) Wp[kh][jt*16+4*lq+i][ct*16+lr]=acc[i];  // C/D map [m89]
  __syncthreads();
  #pragma unroll
  for(int s=0;s<2;s++){
    int idx=tid+s*512; int j=idx>>5, cc=idx&31;
    Wt[j][cc]=Wp[0][j][cc]+Wp[1][j][cc];
  }
  __syncthreads();
  float w2r[2];
  #pragma unroll
  for(int s=0;s<2;s++){
    int idx=tid+s*512; int j=idx>>5, cc=idx&31;
    float s2=0.f;
    if(TRANS){ for(int q=0;q<=j;q++) s2+=Tsh[q][j]*Wt[q][cc]; }
    else     { for(int q=j;q<32;q++) s2+=Tsh[j][q]*Wt[q][cc]; }
    w2r[s]=s2;
  }
  __syncthreads();
  #pragma unroll
  for(int s=0;s<2;s++){
    int idx=tid+s*512; int j=idx>>5, cc=idx&31;
    short h,mi,lo; bsplit3(w2r[s],h,mi,lo);
    W2h[cc][j]=h; W2m[cc][j]=mi; W2l[cc][j]=lo;
  }
  // ---- pass 2: stripe -= V * W2 (K=32), prefetched ----
  { int r=row; vP=(r<m)? *(const f4*)&vf[((size_t)r<<5)+c4] : fz; }
  __syncthreads();      // W2 visible; V2 region (aliases VT/ST) free
  int rt4=w&3, ct2=w>>2;
  int ccol=c0+ct2*16+lr;
  for(int t=0;t<nt;t++){
    short h,mi,lo;
    s4v q0,q1,q2;
    #pragma unroll
    for(int i=0;i<4;i++){
      bsplit3(vP[i],h,mi,lo);
      q0[i]=h; q1[i]=mi; q2[i]=lo;
    }
    *(s4v*)&V2h[row][c4]=q0; *(s4v*)&V2m[row][c4]=q1; *(s4v*)&V2l[row][c4]=q2;
    if(t+1<nt){ int r=(t+1)*64+row;
      vN=(r<m)? *(const f4*)&vf[((size_t)r<<5)+c4] : fz;
    }
    float oldv[4];
    #pragma unroll
    for(int i=0;i<4;i++){
      int r=t*64+rt4*16+4*lq+i;
      oldv[i]=(r<m)? Ab[(size_t)(k0+r)*OUTD+ccol] : 0.f;
    }
    __syncthreads();
    b8v ah=*(const b8v*)&V2h[rt4*16+lr][8*lq];
    b8v am=*(const b8v*)&V2m[rt4*16+lr][8*lq];
    b8v al=*(const b8v*)&V2l[rt4*16+lr][8*lq];
    b8v bh=*(const b8v*)&W2h[ct2*16+lr][8*lq];
    b8v bm=*(const b8v*)&W2m[ct2*16+lr][8*lq];
    b8v bl=*(const b8v*)&W2l[ct2*16+lr][8*lq];
    f4v a2={0.f,0.f,0.f,0.f};
    a2=mfma6(ah,am,al,bh,bm,bl,a2);
    #pragma unroll
    for(int i=0;i<4;i++){
      int r=t*64+rt4*16+4*lq+i;
      if(r<m) Ab[(size_t)(k0+r)*OUTD+ccol]=oldv[i]-a2[i];
    }
    __syncthreads();
    vP=vN;
  }
}

// ---------------- fused geqrf step: trailing update(kb) + panel(kb+1) ------
__global__ __launch_bounds__(512) void k_fgeq(float* A, float* vfull, float* Tws, int kb){
  __shared__ __align__(16) char SM[44544];
  int b=blockIdx.y;
  float* Ab=A+(size_t)b*BSTR;
  if(kb>=0){
    int k0=32*kb;
    size_t voff=32768ull*(size_t)kb - 512ull*(size_t)kb*(size_t)(kb-1);
    const float* vfp=vfull+(size_t)b*VSTR+voff;
    const float* Tb=Tws+((size_t)b*NPAN+kb)*1024;
    int c0=k0+32+32*blockIdx.x;
    blk_update<true>(Ab,vfp,Tb,k0,c0,SM);
    if(blockIdx.x>0) return;
    __syncthreads();
  }
  int kbn=kb+1;
  int k0n=32*kbn;
  int mq=(NN-k0n)>>4;
  int tid=threadIdx.x, c=tid&31, rg=tid>>5;
  float p[64];
  #pragma unroll
  for(int q=0;q<64;q++){ if(q>=mq) break;
    int r=rg+(q<<4);
    p[q]=Ab[(size_t)(k0n+r)*OUTD+k0n+c];
  }
  size_t voffn=32768ull*(size_t)kbn - 512ull*(size_t)kbn*(size_t)(kbn-1);
  panel_factor(p, mq, vfull+(size_t)b*VSTR+voffn, Tws+((size_t)b*NPAN+kbn)*1024, SM);
}

// ---------------- fused orgqr step: form(kb, 8 blocks) + right-apply -------
__global__ __launch_bounds__(512) void k_ford(float* A, const float* __restrict__ vfull,
                                              const float* __restrict__ Tws, int kb){
  __shared__ __align__(16) char SM[44544];
  int b=blockIdx.y;
  float* Ab=A+(size_t)b*BSTR;
  int k0=32*kb;
  size_t voff=32768ull*(size_t)kb - 512ull*(size_t)kb*(size_t)(kb-1);
  const float* vfp=vfull+(size_t)b*VSTR+voff;
  const float* Tb=Tws+((size_t)b*NPAN+kb)*1024;
  if(blockIdx.x>=8){
    int c0=k0+32+32*(blockIdx.x-8);
    blk_update<false>(Ab,vfp,Tb,k0,c0,SM);
    return;
  }
  // form: this block owns rows [z*128, z*128+128) of cols [k0,k0+32)
  int z=blockIdx.x;
  float (*Tsh)[33]=(float(*)[33])(SM);
  float (*Vtf)[33]=(float(*)[33])(SM+4224);
  float (*Sf)[33] =(float(*)[33])(SM+8448);
  int tid=threadIdx.x;
  for(int idx=tid; idx<1024; idx+=512){
    Tsh[idx>>5][idx&31]=Tb[idx];
    Vtf[idx>>5][idx&31]=vfp[idx];
  }
  __syncthreads();
  for(int idx=tid; idx<1024; idx+=512){
    int q=idx>>5, cc=idx&31;
    float s=0.f;
    for(int pp=q;pp<32;pp++) s+=Tsh[q][pp]*Vtf[cc][pp];
    Sf[q][cc]=s;
  }
  __syncthreads();
  int c=tid&31, rg=tid>>5;   // 16 row slots
  for(int rr=rg; rr<128; rr+=16){
    int r=z*128+rr;
    float outv;
    if(r<k0) outv=0.f;
    else{
      int rl=r-k0;
      const float* vrow=vfp+(size_t)rl*32;
      float s=0.f;
      #pragma unroll
      for(int q=0;q<32;q++) s+=vrow[q]*Sf[q][c];
      outv=((rl==c)?1.f:0.f)-s;
    }
    Ab[(size_t)r*OUTD+k0+c]=outv;
  }
}

extern "C" void kernel_launch(void* const* d_in, const int* in_sizes, int n_in,
                              void* d_out, int out_size, void* d_ws, size_t ws_size,
                              hipStream_t stream){
  const float* x0=(const float*)d_in[0];
  const int* ei=(const int*)d_in[1];
  int E=in_sizes[1]/2;
  float* out=(float*)d_out;
  float* degF=(float*)d_ws;                      // N
  float* isq =degF+NN;                           // N
  int*  rowoff=(int*)(isq+NN);                   // N+1
  float* Tws  =(float*)d_ws+4096;                // B*32*1024
  float* vfull=Tws+(size_t)BB*NPAN*1024;         // B*VSTR (18.4MB total ws)

  size_t tot=(size_t)BB*NN*DD;
  k_deg_init<<<1,NN,0,stream>>>(degF);
  k_deg<<<(E+255)/256,256,0,stream>>>(ei,degF,E);
  k_scan<<<1,NN,0,stream>>>(degF,isq,rowoff);
  k_copyx0<<<(int)((tot+255)/256),256,0,stream>>>(x0,out);

  for(int l=0;l<LL;l++){
    float* A=out+(size_t)(l+1)*DD;
    k_conv<<<dim3(NN,BB),256,0,stream>>>(out+(size_t)l*DD,ei,degF,isq,rowoff,A);
    k_fgeq<<<dim3(1,BB),512,0,stream>>>(A,vfull,Tws,-1);
    for(int kb=0;kb<=30;kb++){
      int nc=NN-32*(kb+1);
      k_fgeq<<<dim3(nc/32,BB),512,0,stream>>>(A,vfull,Tws,kb);
    }
    for(int kb=NPAN-1;kb>=0;kb--){
      int nc=NN-32*(kb+1);
      k_ford<<<dim3(8+nc/32,BB),512,0,stream>>>(A,vfull,Tws,kb);
    }
  }
}

// Round 8
// 42726.373 us; speedup vs baseline: 2.0372x; 2.0372x over previous
//
#include <hip/hip_runtime.h>
#include <hip/hip_cooperative_groups.h>
#include <cmath>

namespace cg = cooperative_groups;

#define NN 1024
#define DD 1024
#define BB 8
#define LL 4
#define OUTD (DD*(LL+1))   // 5120
#define NB 32
#define NPAN 32
#define BSTR ((size_t)NN*OUTD)
#define VSTR 540672ull     // per-batch ws floats for full-V dump

typedef short b8v __attribute__((ext_vector_type(8)));
typedef float f4v __attribute__((ext_vector_type(4)));

__device__ __forceinline__ unsigned short f2bf(float x){
  unsigned u=__float_as_uint(x);
  return (unsigned short)((u + 0x7FFFu + ((u>>16)&1u))>>16);
}
__device__ __forceinline__ float bf2f(unsigned short h){
  return __uint_as_float(((unsigned)h)<<16);
}
// 3-split: x = h + m + l -> 6-product MFMA == fp32-equivalent (validated r5/r6)
__device__ __forceinline__ void bsplit3(float x, short& h, short& m, short& l){
  unsigned short hh=f2bf(x);
  float r1=x-bf2f(hh);
  unsigned short mm=f2bf(r1);
  float r2=r1-bf2f(mm);
  h=(short)hh; m=(short)mm; l=(short)f2bf(r2);
}
__device__ __forceinline__ f4v mfma6(b8v ah,b8v am,b8v al,b8v bh,b8v bm,b8v bl,f4v acc){
  acc=__builtin_amdgcn_mfma_f32_16x16x32_bf16(al,bh,acc,0,0,0);
  acc=__builtin_amdgcn_mfma_f32_16x16x32_bf16(ah,bl,acc,0,0,0);
  acc=__builtin_amdgcn_mfma_f32_16x16x32_bf16(am,bm,acc,0,0,0);
  acc=__builtin_amdgcn_mfma_f32_16x16x32_bf16(am,bh,acc,0,0,0);
  acc=__builtin_amdgcn_mfma_f32_16x16x32_bf16(ah,bm,acc,0,0,0);
  acc=__builtin_amdgcn_mfma_f32_16x16x32_bf16(ah,bh,acc,0,0,0);
  return acc;
}
__device__ __forceinline__ size_t voff(int kb){
  return 32768ull*(size_t)kb - 512ull*(size_t)kb*(size_t)(kb-1);
}

// ---------------- setup ----------------
__global__ void k_deg_init(float* degF){ degF[threadIdx.x]=0.f; }

__global__ void k_deg(const int* __restrict__ ei, float* __restrict__ degF, int E){
  int e=blockIdx.x*blockDim.x+threadIdx.x;
  if(e<E) atomicAdd(&degF[ei[2*e]],1.f);
}

__global__ void k_scan(const float* __restrict__ degF, float* __restrict__ isq, int* __restrict__ rowoff){
  __shared__ int s[NN];
  int i=threadIdx.x;
  int d=(int)degF[i];
  s[i]=d; __syncthreads();
  for(int off=1;off<NN;off<<=1){
    int v=(i>=off)?s[i-off]:0;
    __syncthreads();
    s[i]+=v;
    __syncthreads();
  }
  if(i==0) rowoff[0]=0;
  rowoff[i+1]=s[i];
  isq[i]=(d>0)?(float)(1.0/sqrt((double)d)):0.f;
}

__global__ void k_copyx0(const float* __restrict__ x0, float* __restrict__ out){
  size_t t=(size_t)blockIdx.x*blockDim.x+threadIdx.x;
  if(t>=(size_t)BB*NN*DD) return;
  int d=(int)(t&(DD-1)); size_t bn=t>>10;
  out[bn*OUTD+d]=x0[t];
}

// ---------------- graph conv (r6-verbatim) ----------------
__global__ void k_conv(const float* __restrict__ xin, const int* __restrict__ ei,
                       const float* __restrict__ degF, const float* __restrict__ isq,
                       const int* __restrict__ rowoff, float* Aout){
  int i=blockIdx.x, b=blockIdx.y;
  __shared__ int sdst[64]; __shared__ float sw[64];
  int r0=rowoff[i], r1=rowoff[i+1];
  int cnt=r1-r0; if(cnt>64) cnt=64;
  float di=degF[i], isqi=isq[i];
  for(int e=threadIdx.x;e<cnt;e+=blockDim.x){
    int dv=ei[2*(r0+e)+1];
    sdst[e]=dv; sw[e]=isqi*isq[dv];
  }
  __syncthreads();
  float cm=((float)(r1-r0))*di/fmaxf(di,1.f);
  const float* xi=xin+((size_t)(b*NN+i))*OUTD;
  float* ao=Aout+((size_t)(b*NN+i))*OUTD;
  for(int d=threadIdx.x; d<DD; d+=blockDim.x){
    float acc=0.f;
    for(int e=0;e<cnt;e++) acc+=sw[e]*xin[((size_t)(b*NN+sdst[e]))*OUTD+d];
    ao[d]=0.5f*acc+0.5f*cm*xi[d];
  }
}

// ---------------- in-register Householder panel factor (512 thr, r6-verbatim)
__device__ void panel_factor(float* p, int mq, float* vfslot, float* Twslot, char* SM){
  float (*Tsh)[33]=(float(*)[33])(SM);
  float* vsh =(float*)(SM+16896);
  float* red =(float*)(SM+20992);
  float* s_sh=(float*)(SM+23104);
  float* taus=(float*)(SM+23232);
  float* meta=(float*)(SM+23360);
  int tid=threadIdx.x, c=tid&31, rg=tid>>5;
  for(int idx=tid; idx<32*33; idx+=512) ((float*)Tsh)[idx]=0.f;
  __syncthreads();
  #pragma unroll 1
  for(int j=0;j<NB;j++){
    if(c==j){
      float ss=0.f;
      #pragma unroll
      for(int q=0;q<64;q++) if(q<mq){
        int r=rg+(q<<4);
        if(r>j) ss+=p[q]*p[q];
        else if(r==j) meta[2]=p[q];
      }
      red[rg*33+32]=ss;
    }
    __syncthreads();                                   // B1
    if(tid<16){
      float v=red[tid*33+32];
      #pragma unroll
      for(int o=8;o>0;o>>=1) v+=__shfl_xor(v,o,16);
      if(tid==0){
        float alpha=meta[2], ssq=v, tau, scale;
        if(ssq==0.f){tau=0.f;scale=0.f;}
        else{
          double bn=sqrt((double)alpha*(double)alpha+(double)ssq);
          float beta=(alpha>=0.f)?(float)(-bn):(float)bn; // -sign(alpha)*norm
          tau=(beta-alpha)/beta; scale=1.f/(alpha-beta);
        }
        taus[j]=tau; meta[0]=scale;
      }
    }
    __syncthreads();                                   // B2
    float tau=taus[j], scale=meta[0];
    if(c==j){
      #pragma unroll
      for(int q=0;q<64;q++) if(q<mq){
        int r=rg+(q<<4);
        if(r>j){p[q]*=scale; vsh[r]=p[q];}
        else if(r==j) vsh[r]=1.f;
      }
    }
    __syncthreads();                                   // B3
    {
      float acc=0.f;
      #pragma unroll
      for(int q=0;q<64;q++) if(q<mq){
        int r=rg+(q<<4);
        if(r>=j) acc+=vsh[r]*p[q];
      }
      red[rg*33+c]=acc;
    }
    __syncthreads();                                   // B4
    {
      int c2=tid>>4, q2=tid&15;
      float v=red[q2*33+c2];
      #pragma unroll
      for(int o=8;o>0;o>>=1) v+=__shfl_xor(v,o,16);
      if(q2==0) s_sh[c2]=v;
    }
    __syncthreads();                                   // B5
    if(c>j){
      float wv=tau*s_sh[c];
      #pragma unroll
      for(int q=0;q<64;q++) if(q<mq){
        int r=rg+(q<<4);
        if(r>=j) p[q]-=wv*vsh[r];
      }
    }
    if(tid<j){
      float s=0.f;
      for(int q2=tid;q2<j;q2++) s+=Tsh[tid][q2]*s_sh[q2];
      Tsh[tid][j]=-tau*s;
    } else if(tid==j) Tsh[j][j]=tau;
  }
  __syncthreads();
  #pragma unroll
  for(int q=0;q<64;q++) if(q<mq){
    int r=rg+(q<<4);
    vfslot[(size_t)r*32+c]=(r>c)?p[q]:((r==c)?1.f:0.f);
  }
  for(int idx=tid; idx<1024; idx+=512) Twslot[idx]=Tsh[idx>>5][idx&31];
}

// ---------------- block reflector apply (r6-verbatim, 3-split MFMA) --------
template<bool TRANS>
__device__ void blk_update(float* Ab, const float* __restrict__ vf, const float* __restrict__ Tb,
                           int k0, int c0, char* SM){
  float (*Tsh)[33]=(float(*)[33])(SM);              // 4224
  float (*Wt)[33] =(float(*)[33])(SM+4224);         // 4224
  float (*Wp)[32][33]=(float(*)[32][33])(SM+8448);  // 8448
  short (*W2h)[40]=(short(*)[40])(SM+8448);         // aliases Wp (dead by then)
  short (*W2m)[40]=(short(*)[40])(SM+11008);
  short (*W2l)[40]=(short(*)[40])(SM+13568);
  short (*VTh)[72]=(short(*)[72])(SM+16896);
  short (*VTm)[72]=(short(*)[72])(SM+21504);
  short (*VTl)[72]=(short(*)[72])(SM+26112);
  short (*STh)[72]=(short(*)[72])(SM+30720);
  short (*STm)[72]=(short(*)[72])(SM+35328);
  short (*STl)[72]=(short(*)[72])(SM+39936);        // -> 44544
  short (*V2h)[40]=(short(*)[40])(SM+16896);        // pass2 aliases
  short (*V2m)[40]=(short(*)[40])(SM+22016);
  short (*V2l)[40]=(short(*)[40])(SM+27136);
  int tid=threadIdx.x, w=tid>>6, lane=tid&63, lr=lane&15, lq=lane>>4;
  int m=NN-k0;
  for(int idx=tid; idx<1024; idx+=512) Tsh[idx>>5][idx&31]=Tb[idx];
  // pass 1: W = V^T * stripe (K=m). wave w -> (jt,ct,K-half)
  int jt=w&1, ct=(w>>1)&1, kh=w>>2;
  f4v acc={0.f,0.f,0.f,0.f};
  for(int rt=0; rt<m; rt+=64){
    __syncthreads();
    for(int idx=tid; idx<2048; idx+=512){
      int rr=idx>>5, j=idx&31; int r=rt+rr;
      float v=(r<m)? vf[(size_t)r*32+j] : 0.f;
      short h,mi,lo; bsplit3(v,h,mi,lo);
      VTh[j][rr]=h; VTm[j][rr]=mi; VTl[j][rr]=lo;
    }
    for(int idx=tid; idx<2048; idx+=512){
      int rr=idx>>5, cc=idx&31; int r=rt+rr;
      float v=(r<m)? Ab[(size_t)(k0+r)*OUTD+c0+cc] : 0.f;
      short h,mi,lo; bsplit3(v,h,mi,lo);
      STh[cc][rr]=h; STm[cc][rr]=mi; STl[cc][rr]=lo;
    }
    __syncthreads();
    int ko=kh*32+8*lq;
    b8v ah=*(const b8v*)&VTh[jt*16+lr][ko];
    b8v am=*(const b8v*)&VTm[jt*16+lr][ko];
    b8v al=*(const b8v*)&VTl[jt*16+lr][ko];
    b8v bh=*(const b8v*)&STh[ct*16+lr][ko];
    b8v bm=*(const b8v*)&STm[ct*16+lr][ko];
    b8v bl=*(const b8v*)&STl[ct*16+lr][ko];
    acc=mfma6(ah,am,al,bh,bm,bl,acc);
  }
  __syncthreads();
  // C/D layout: col=lane&15, row=4*(lane>>4)+i [verified m89]
  #pragma unroll
  for(int i=0;i<4;i++) Wp[kh][jt*16+4*lq+i][ct*16+lr]=acc[i];
  __syncthreads();
  #pragma unroll
  for(int s=0;s<2;s++){
    int idx=tid+s*512; int j=idx>>5, cc=idx&31;
    Wt[j][cc]=Wp[0][j][cc]+Wp[1][j][cc];
  }
  __syncthreads();
  float w2r[2];
  #pragma unroll
  for(int s=0;s<2;s++){
    int idx=tid+s*512; int j=idx>>5, cc=idx&31;
    float s2=0.f;
    if(TRANS){ for(int q=0;q<=j;q++) s2+=Tsh[q][j]*Wt[q][cc]; }
    else     { for(int q=j;q<32;q++) s2+=Tsh[j][q]*Wt[q][cc]; }
    w2r[s]=s2;
  }
  __syncthreads();        // all Wt reads done before W2 overwrites Wp region
  #pragma unroll
  for(int s=0;s<2;s++){
    int idx=tid+s*512; int j=idx>>5, cc=idx&31;
    short h,mi,lo; bsplit3(w2r[s],h,mi,lo);
    W2h[cc][j]=h; W2m[cc][j]=mi; W2l[cc][j]=lo;
  }
  // pass 2: stripe -= V * W2. wave w -> (row16 rt4, col16 ct2)
  int rt4=w&3, ct2=w>>2;
  for(int rt=0; rt<m; rt+=64){
    __syncthreads();
    for(int idx=tid; idx<2048; idx+=512){
      int rr=idx>>5, j=idx&31; int r=rt+rr;
      float v=(r<m)? vf[(size_t)r*32+j]:0.f;
      short h,mi,lo; bsplit3(v,h,mi,lo);
      V2h[rr][j]=h; V2m[rr][j]=mi; V2l[rr][j]=lo;
    }
    __syncthreads();
    b8v ah=*(const b8v*)&V2h[rt4*16+lr][8*lq];
    b8v am=*(const b8v*)&V2m[rt4*16+lr][8*lq];
    b8v al=*(const b8v*)&V2l[rt4*16+lr][8*lq];
    b8v bh=*(const b8v*)&W2h[ct2*16+lr][8*lq];
    b8v bm=*(const b8v*)&W2m[ct2*16+lr][8*lq];
    b8v bl=*(const b8v*)&W2l[ct2*16+lr][8*lq];
    f4v a2={0.f,0.f,0.f,0.f};
    a2=mfma6(ah,am,al,bh,bm,bl,a2);
    int ccol=c0+ct2*16+lr;
    #pragma unroll
    for(int i=0;i<4;i++){
      int r=rt+rt4*16+4*lq+i;
      if(r<m) Ab[(size_t)(k0+r)*OUTD+ccol]-=a2[i];
    }
  }
  __syncthreads();
}

// ---------------- Q-panel formation, one 128-row chunk ----------------------
__device__ void form_chunk(float* Ab, const float* __restrict__ vf, const float* __restrict__ Tb,
                           int k0, int z, char* SM){
  float (*Tsh)[33]=(float(*)[33])(SM);
  float (*Vtf)[33]=(float(*)[33])(SM+4224);
  float (*Sf)[33] =(float(*)[33])(SM+8448);
  int tid=threadIdx.x;
  for(int idx=tid; idx<1024; idx+=512){
    Tsh[idx>>5][idx&31]=Tb[idx];
    Vtf[idx>>5][idx&31]=vf[idx];
  }
  __syncthreads();
  for(int idx=tid; idx<1024; idx+=512){
    int q=idx>>5, cc=idx&31;
    float s=0.f;
    for(int pp=q;pp<32;pp++) s+=Tsh[q][pp]*Vtf[cc][pp];
    Sf[q][cc]=s;
  }
  __syncthreads();
  int c=tid&31, rg=tid>>5;   // 16 row slots
  for(int rr=rg; rr<128; rr+=16){
    int r=z*128+rr;
    float outv;
    if(r<k0) outv=0.f;
    else{
      int rl=r-k0;
      const float* vrow=vf+(size_t)rl*32;
      float s=0.f;
      #pragma unroll
      for(int q=0;q<32;q++) s+=vrow[q]*Sf[q][c];
      outv=((rl==c)?1.f:0.f)-s;
    }
    Ab[(size_t)r*OUTD+k0+c]=outv;
  }
  __syncthreads();
}

// ---------------- cooperative per-layer QR (geqrf w/ lookahead + orgqr) ----
__global__ __launch_bounds__(512) void k_layer(float* A, float* vfull, float* Tws){
  cg::grid_group grid = cg::this_grid();
  __shared__ __align__(16) char SM[44544];
  int bid=blockIdx.x, tid=threadIdx.x;
  int c=tid&31, rg=tid>>5;

  // panel 0
  if(bid<8){
    float* Ab=A+(size_t)bid*BSTR;
    int mq=NN>>4;
    float p[64];
    #pragma unroll
    for(int q=0;q<64;q++) if(q<mq){
      int r=rg+(q<<4);
      p[q]=Ab[(size_t)r*OUTD+c];
    }
    panel_factor(p,mq,vfull+(size_t)bid*VSTR,Tws+(size_t)bid*NPAN*1024,SM);
  }
  grid.sync();

  // geqrf with lookahead
  for(int kb=0;kb<=30;kb++){
    int k0=32*kb;
    // step A: update next-panel cols only
    if(bid<8){
      blk_update<true>(A+(size_t)bid*BSTR, vfull+(size_t)bid*VSTR+voff(kb),
                       Tws+((size_t)bid*NPAN+kb)*1024, k0, k0+32, SM);
    }
    grid.sync();
    // step B: panel(kb+1) || update(kb) on far cols
    if(bid<8){
      int kbn=kb+1, k0n=32*kbn, mq=(NN-k0n)>>4;
      float* Ab=A+(size_t)bid*BSTR;
      float p[64];
      #pragma unroll
      for(int q=0;q<64;q++) if(q<mq){
        int r=rg+(q<<4);
        p[q]=Ab[(size_t)(k0n+r)*OUTD+k0n+c];
      }
      panel_factor(p,mq,vfull+(size_t)bid*VSTR+voff(kbn),
                   Tws+((size_t)bid*NPAN+kbn)*1024,SM);
    } else {
      int per=30-kb, t=bid-8;
      if(per>0 && t<8*per){
        int b=t/per, cb=t%per;
        blk_update<true>(A+(size_t)b*BSTR, vfull+(size_t)b*VSTR+voff(kb),
                         Tws+((size_t)b*NPAN+kb)*1024, k0, k0+64+32*cb, SM);
      }
    }
    grid.sync();
  }

  // orgqr: per kb, form(kb) || right-apply(kb) (disjoint columns)
  for(int kb=NPAN-1;kb>=0;kb--){
    int k0=32*kb, nu=NPAN-1-kb, ntk=64+8*nu;
    for(int task=bid; task<ntk; task+=256){
      if(task<64){
        int b=task>>3, z=task&7;
        form_chunk(A+(size_t)b*BSTR, vfull+(size_t)b*VSTR+voff(kb),
                   Tws+((size_t)b*NPAN+kb)*1024, k0, z, SM);
      } else {
        int t=task-64, b=t/nu, cb=t%nu;
        blk_update<false>(A+(size_t)b*BSTR, vfull+(size_t)b*VSTR+voff(kb),
                          Tws+((size_t)b*NPAN+kb)*1024, k0, k0+32+32*cb, SM);
      }
    }
    grid.sync();
  }
}

extern "C" void kernel_launch(void* const* d_in, const int* in_sizes, int n_in,
                              void* d_out, int out_size, void* d_ws, size_t ws_size,
                              hipStream_t stream){
  const float* x0=(const float*)d_in[0];
  const int* ei=(const int*)d_in[1];
  int E=in_sizes[1]/2;
  float* out=(float*)d_out;
  float* degF=(float*)d_ws;                      // N
  float* isq =degF+NN;                           // N
  int*  rowoff=(int*)(isq+NN);                   // N+1
  float* Tws  =(float*)d_ws+4096;                // B*32*1024
  float* vfull=Tws+(size_t)BB*NPAN*1024;         // B*VSTR (18.4MB total ws)

  size_t tot=(size_t)BB*NN*DD;
  k_deg_init<<<1,NN,0,stream>>>(degF);
  k_deg<<<(E+255)/256,256,0,stream>>>(ei,degF,E);
  k_scan<<<1,NN,0,stream>>>(degF,isq,rowoff);
  k_copyx0<<<(int)((tot+255)/256),256,0,stream>>>(x0,out);

  for(int l=0;l<LL;l++){
    float* A=out+(size_t)(l+1)*DD;
    k_conv<<<dim3(NN,BB),256,0,stream>>>(out+(size_t)l*DD,ei,degF,isq,rowoff,A);
    void* kargs[]={(void*)&A,(void*)&vfull,(void*)&Tws};
    hipLaunchCooperativeKernel(reinterpret_cast<void*>(k_layer),
                               dim3(256),dim3(512),kargs,0,stream);
  }
}

// Round 9
// 31653.049 us; speedup vs baseline: 2.7499x; 1.3498x over previous
//
#include <hip/hip_runtime.h>
#include <hip/hip_cooperative_groups.h>
#include <cmath>

namespace cg = cooperative_groups;

#define NN 1024
#define DD 1024
#define BB 8
#define LL 4
#define OUTD (DD*(LL+1))   // 5120
#define NB 32
#define NPAN 32
#define BSTR ((size_t)NN*OUTD)
#define VSTR 540672ull     // per-batch ws floats for V^T dump (sum of 32*m_i)

typedef short b8v __attribute__((ext_vector_type(8)));
typedef float f4v __attribute__((ext_vector_type(4)));
typedef float f4  __attribute__((ext_vector_type(4)));

__device__ __forceinline__ unsigned short f2bf(float x){
  unsigned u=__float_as_uint(x);
  return (unsigned short)((u + 0x7FFFu + ((u>>16)&1u))>>16);
}
__device__ __forceinline__ float bf2f(unsigned short h){
  return __uint_as_float(((unsigned)h)<<16);
}
// 3-split: x = h + m + l -> 6-product MFMA == fp32-equivalent (validated r5/r6/r8)
__device__ __forceinline__ void bsplit3(float x, short& h, short& m, short& l){
  unsigned short hh=f2bf(x);
  float r1=x-bf2f(hh);
  unsigned short mm=f2bf(r1);
  float r2=r1-bf2f(mm);
  h=(short)hh; m=(short)mm; l=(short)f2bf(r2);
}
__device__ __forceinline__ f4v mfma6(b8v ah,b8v am,b8v al,b8v bh,b8v bm,b8v bl,f4v acc){
  acc=__builtin_amdgcn_mfma_f32_16x16x32_bf16(al,bh,acc,0,0,0);
  acc=__builtin_amdgcn_mfma_f32_16x16x32_bf16(ah,bl,acc,0,0,0);
  acc=__builtin_amdgcn_mfma_f32_16x16x32_bf16(am,bm,acc,0,0,0);
  acc=__builtin_amdgcn_mfma_f32_16x16x32_bf16(am,bh,acc,0,0,0);
  acc=__builtin_amdgcn_mfma_f32_16x16x32_bf16(ah,bm,acc,0,0,0);
  acc=__builtin_amdgcn_mfma_f32_16x16x32_bf16(ah,bh,acc,0,0,0);
  return acc;
}
__device__ __forceinline__ size_t voff(int kb){
  return 32768ull*(size_t)kb - 512ull*(size_t)kb*(size_t)(kb-1);
}

// ---------------- setup ----------------
__global__ void k_deg_init(float* degF){ degF[threadIdx.x]=0.f; }

__global__ void k_deg(const int* __restrict__ ei, float* __restrict__ degF, int E){
  int e=blockIdx.x*blockDim.x+threadIdx.x;
  if(e<E) atomicAdd(&degF[ei[2*e]],1.f);
}

__global__ void k_scan(const float* __restrict__ degF, float* __restrict__ isq, int* __restrict__ rowoff){
  __shared__ int s[NN];
  int i=threadIdx.x;
  int d=(int)degF[i];
  s[i]=d; __syncthreads();
  for(int off=1;off<NN;off<<=1){
    int v=(i>=off)?s[i-off]:0;
    __syncthreads();
    s[i]+=v;
    __syncthreads();
  }
  if(i==0) rowoff[0]=0;
  rowoff[i+1]=s[i];
  isq[i]=(d>0)?(float)(1.0/sqrt((double)d)):0.f;
}

__global__ void k_copyx0(const float* __restrict__ x0, float* __restrict__ out){
  size_t t=(size_t)blockIdx.x*blockDim.x+threadIdx.x;
  if(t>=(size_t)BB*NN*DD) return;
  int d=(int)(t&(DD-1)); size_t bn=t>>10;
  out[bn*OUTD+d]=x0[t];
}

// ---------------- graph conv ----------------
__global__ void k_conv(const float* __restrict__ xin, const int* __restrict__ ei,
                       const float* __restrict__ degF, const float* __restrict__ isq,
                       const int* __restrict__ rowoff, float* Aout){
  int i=blockIdx.x, b=blockIdx.y;
  __shared__ int sdst[64]; __shared__ float sw[64];
  int r0=rowoff[i], r1=rowoff[i+1];
  int cnt=r1-r0; if(cnt>64) cnt=64;
  float di=degF[i], isqi=isq[i];
  for(int e=threadIdx.x;e<cnt;e+=blockDim.x){
    int dv=ei[2*(r0+e)+1];
    sdst[e]=dv; sw[e]=isqi*isq[dv];
  }
  __syncthreads();
  float cm=((float)(r1-r0))*di/fmaxf(di,1.f);
  const float* xi=xin+((size_t)(b*NN+i))*OUTD;
  float* ao=Aout+((size_t)(b*NN+i))*OUTD;
  for(int d=threadIdx.x; d<DD; d+=blockDim.x){
    float acc=0.f;
    for(int e=0;e<cnt;e++) acc+=sw[e]*xin[((size_t)(b*NN+sdst[e]))*OUTD+d];
    ao[d]=0.5f*acc+0.5f*cm*xi[d];
  }
}

// ---------------- panel factor: quarter-wave column groups -------------------
// 512 threads: col c=tid>>4, lane rw=tid&15 owns rows r=rw+16q (q<mq).
// 1 barrier/column (vsh double-buffered); T built in parallel afterward from
// saved larft dot vectors. Writes V^T [32][m] + T [32][32] to ws.
__device__ void panel_factor2(float* p, int mq, int m, float* __restrict__ vfT,
                              float* __restrict__ Twslot, char* SM){
  float* vsh2=(float*)SM;                    // 2*1024 f32 (double-buffered v)
  float (*Ssav)[33]=(float(*)[33])(SM+8192); // saved dot vectors
  float* taus=(float*)(SM+12416);            // 32
  int tid=threadIdx.x, c=tid>>4, rw=tid&15;
  #pragma unroll 1
  for(int j=0;j<NB;j++){
    float* vb=vsh2+((j&1)<<10);
    if(c==j){
      float ss=0.f, al=0.f;
      #pragma unroll
      for(int q=0;q<64;q++) if(q<mq){
        int r=rw+(q<<4);
        float pv=p[q];
        if(r>j) ss+=pv*pv; else if(r==j) al=pv;
      }
      #pragma unroll
      for(int o=8;o>0;o>>=1){ ss+=__shfl_xor(ss,o,16); al+=__shfl_xor(al,o,16); }
      float tau,scale;
      if(ss==0.f){ tau=0.f; scale=0.f; }
      else{
        double bn=sqrt((double)al*(double)al+(double)ss);
        float beta=(al>=0.f)?(float)(-bn):(float)bn;   // -sign(alpha)*norm
        tau=(beta-al)/beta; scale=1.f/(al-beta);
      }
      #pragma unroll
      for(int q=0;q<64;q++) if(q<mq){
        int r=rw+(q<<4);
        if(r>j){ p[q]*=scale; vb[r]=p[q]; }
        else if(r==j) vb[r]=1.f;
      }
      if(rw==0) taus[j]=tau;
    }
    __syncthreads();
    float tau=taus[j];
    float sc=0.f;
    #pragma unroll
    for(int q=0;q<64;q++) if(q<mq){
      int r=rw+(q<<4);
      if(r>=j) sc+=vb[r]*p[q];
    }
    #pragma unroll
    for(int o=8;o>0;o>>=1) sc+=__shfl_xor(sc,o,16);
    if(c>j){
      float wv=tau*sc;
      #pragma unroll
      for(int q=0;q<64;q++) if(q<mq){
        int r=rw+(q<<4);
        if(r>=j) p[q]-=wv*vb[r];
      }
    } else if(c<j && rw==0) Ssav[j][c]=sc;
  }
  __syncthreads();
  // T build (all rows parallel; lane rw holds T[c][rw], T[c][rw+16])
  float tq0=0.f,tq1=0.f;
  #pragma unroll
  for(int j=0;j<32;j++){
    float tj=taus[j];
    float s=((rw<j)?tq0*Ssav[j][rw]:0.f)+((rw+16<j)?tq1*Ssav[j][rw+16]:0.f);
    #pragma unroll
    for(int o=8;o>0;o>>=1) s+=__shfl_xor(s,o,16);
    float val=-tj*s;
    if(j>c){ if((j&15)==rw){ if(j<16) tq0=val; else tq1=val; } }
    else if(j==c){ if((j&15)==rw){ if(j<16) tq0=tj; else tq1=tj; } }
  }
  Twslot[(c<<5)+rw]=tq0;
  Twslot[(c<<5)+rw+16]=tq1;
  // V^T writeback (explicit unit diag / zeros above)
  #pragma unroll
  for(int q=0;q<64;q++) if(q<mq){
    int r=rw+(q<<4);
    vfT[(size_t)c*m+r]=(r>c)?p[q]:((r==c)?1.f:0.f);
  }
  __syncthreads();
}

// ---------------- block reflector apply: direct-global MFMA ------------------
// TRANS=true : cols <- (I - V T^T V^T) cols   (geqrf)
// TRANS=false: cols <- (I - V T   V^T) cols   (orgqr)
// Fragments loaded straight from global (vfT is k-contiguous for both passes);
// only T/W/W2 in LDS. 5 barriers total, zero per-K-tile sync.
template<bool TRANS>
__device__ void blk_update(float* __restrict__ Ab, const float* __restrict__ vfT,
                           const float* __restrict__ Tb, int k0, int c0, char* SM){
  float (*Tsh)[33]=(float(*)[33])(SM);              // 4224
  float (*Wt)[33] =(float(*)[33])(SM+4224);         // 4224
  float (*Wp)[32][33]=(float(*)[32][33])(SM+8448);  // 8448 -> 16896
  short (*W2h)[40]=(short(*)[40])(SM+8448);         // aliases Wp (dead by then)
  short (*W2m)[40]=(short(*)[40])(SM+11008);
  short (*W2l)[40]=(short(*)[40])(SM+13568);        // -> 16128
  int tid=threadIdx.x, w=tid>>6, lane=tid&63, lr=lane&15, lq=lane>>4;
  int m=NN-k0;
  for(int idx=tid; idx<1024; idx+=512) Tsh[idx>>5][idx&31]=Tb[idx];
  // ---- pass 1: W = V^T * stripe (K=m) ----
  int jt=w&1, ct=(w>>1)&1, kh=w>>2;
  int ja=jt*16+lr, cb=ct*16+lr;
  int ko=(kh<<5)+(lq<<3);
  f4v acc={0.f,0.f,0.f,0.f};
  for(int rt=0; rt<m; rt+=64){
    int kk=rt+ko;
    float av[8], sv[8];
    if(kk<m){
      *(f4*)&av[0]=*(const f4*)&vfT[(size_t)ja*m+kk];
      *(f4*)&av[4]=*(const f4*)&vfT[(size_t)ja*m+kk+4];
      const float* sp=&Ab[(size_t)(k0+kk)*OUTD + (c0+cb)];
      #pragma unroll
      for(int e=0;e<8;e++) sv[e]=sp[(size_t)e*OUTD];
    } else {
      #pragma unroll
      for(int e=0;e<8;e++){ av[e]=0.f; sv[e]=0.f; }
    }
    b8v ah,am2,al2,bh,bm2,bl2;
    #pragma unroll
    for(int e=0;e<8;e++){
      short h,mi,lo;
      bsplit3(av[e],h,mi,lo); ah[e]=h; am2[e]=mi; al2[e]=lo;
      bsplit3(sv[e],h,mi,lo); bh[e]=h; bm2[e]=mi; bl2[e]=lo;
    }
    acc=mfma6(ah,am2,al2,bh,bm2,bl2,acc);
  }
  // C/D layout: col=lane&15, row=4*(lane>>4)+i [verified m89]
  #pragma unroll
  for(int i=0;i<4;i++) Wp[kh][jt*16+4*lq+i][ct*16+lr]=acc[i];
  __syncthreads();
  #pragma unroll
  for(int s=0;s<2;s++){
    int idx=tid+(s<<9), j=idx>>5, cc=idx&31;
    Wt[j][cc]=Wp[0][j][cc]+Wp[1][j][cc];
  }
  __syncthreads();
  // ---- T apply (f32) ----
  float w2r[2];
  #pragma unroll
  for(int s=0;s<2;s++){
    int idx=tid+(s<<9), cc=idx>>5, j=idx&31;
    float s2=0.f;
    if(TRANS){ for(int q=0;q<=j;q++) s2+=Tsh[q][j]*Wt[q][cc]; }
    else     { for(int q=j;q<32;q++) s2+=Tsh[j][q]*Wt[q][cc]; }
    w2r[s]=s2;
  }
  __syncthreads();   // Wt/Wp reads done -> W2 region free
  #pragma unroll
  for(int s=0;s<2;s++){
    int idx=tid+(s<<9), cc=idx>>5, j=idx&31;
    short h,mi,lo; bsplit3(w2r[s],h,mi,lo);
    W2h[cc][j]=h; W2m[cc][j]=mi; W2l[cc][j]=lo;
  }
  __syncthreads();
  // ---- pass 2: stripe -= V * W2 (K=32) ----
  int rt4=w&3, ct2=w>>2;
  int cb2=ct2*16+lr;
  b8v wh=*(const b8v*)&W2h[cb2][lq<<3];
  b8v wm=*(const b8v*)&W2m[cb2][lq<<3];
  b8v wl=*(const b8v*)&W2l[cb2][lq<<3];
  int ccol=c0+cb2;
  for(int rt=0; rt<m; rt+=64){
    int rbase=rt+rt4*16;
    if(rbase<m){
      float vv[8];
      #pragma unroll
      for(int e=0;e<8;e++) vv[e]=vfT[(size_t)(8*lq+e)*m + rbase+lr];
      b8v ah,am2,al2;
      #pragma unroll
      for(int e=0;e<8;e++){ short h,mi,lo; bsplit3(vv[e],h,mi,lo); ah[e]=h; am2[e]=mi; al2[e]=lo; }
      f4v a2={0.f,0.f,0.f,0.f};
      a2=mfma6(ah,am2,al2,wh,wm,wl,a2);
      #pragma unroll
      for(int i=0;i<4;i++){
        int r=rbase+4*lq+i;
        Ab[(size_t)(k0+r)*OUTD+ccol]-=a2[i];
      }
    }
  }
  __syncthreads();
}

// ---------------- Q-panel formation, one 128-row chunk -----------------------
__device__ void form_chunk(float* __restrict__ Ab, const float* __restrict__ vfT,
                           const float* __restrict__ Tb, int k0, int z, int m, char* SM){
  float (*Tsh)[33]=(float(*)[33])(SM);
  float (*Vtf)[33]=(float(*)[33])(SM+4224);   // V^T top: Vtf[j][i]=V[i][j]
  float (*Sf)[33] =(float(*)[33])(SM+8448);
  int tid=threadIdx.x;
  for(int idx=tid; idx<1024; idx+=512){
    int j=idx>>5, i=idx&31;
    Tsh[j][i]=Tb[idx];
    Vtf[j][i]=vfT[(size_t)j*m+i];
  }
  __syncthreads();
  // Sf[q][cc] = sum_{p>=q} T[q][p] * V[cc][p] = sum Tsh[q][p]*Vtf[p][cc]
  for(int idx=tid; idx<1024; idx+=512){
    int q=idx>>5, cc=idx&31;
    float s=0.f;
    for(int pp2=q;pp2<32;pp2++) s+=Tsh[q][pp2]*Vtf[pp2][cc];
    Sf[q][cc]=s;
  }
  __syncthreads();
  int c2=tid&31, rg=tid>>5;
  for(int rr=rg; rr<128; rr+=16){
    int r=(z<<7)+rr;
    float outv;
    if(r<k0) outv=0.f;
    else{
      int rl=r-k0;
      float s=0.f;
      #pragma unroll
      for(int q=0;q<32;q++) s+=vfT[(size_t)q*m+rl]*Sf[q][c2];
      outv=((rl==c2)?1.f:0.f)-s;
    }
    Ab[(size_t)r*OUTD+k0+c2]=outv;
  }
  __syncthreads();
}

// ---------------- cooperative per-layer QR -----------------------------------
__global__ __launch_bounds__(512) void k_layer(float* A, float* vfull, float* Tws){
  cg::grid_group grid = cg::this_grid();
  __shared__ __align__(16) char SM[16896];
  int bid=blockIdx.x, tid=threadIdx.x;
  int c=tid>>4, rw=tid&15;

  // panel 0
  if(bid<8){
    float* Ab=A+(size_t)bid*BSTR;
    float p[64];
    #pragma unroll
    for(int q=0;q<64;q++){ int r=rw+(q<<4); p[q]=Ab[(size_t)r*OUTD+c]; }
    panel_factor2(p,64,NN,vfull+(size_t)bid*VSTR,Tws+(size_t)bid*NPAN*1024,SM);
  }
  grid.sync();

  // geqrf: fused {lookahead-update + panel(kb+1)} || far updates
  for(int kb=0;kb<=30;kb++){
    int k0=kb<<5;
    if(bid<8){
      float* Ab=A+(size_t)bid*BSTR;
      blk_update<true>(Ab, vfull+(size_t)bid*VSTR+voff(kb),
                       Tws+((size_t)bid*NPAN+kb)*1024, k0, k0+32, SM);
      int k0n=k0+32, mq=(NN-k0n)>>4, mn=NN-k0n;
      float p[64];
      #pragma unroll
      for(int q=0;q<64;q++){
        p[q]=0.f;
        if(q<mq){ int r=rw+(q<<4); p[q]=Ab[(size_t)(k0n+r)*OUTD+k0n+c]; }
      }
      panel_factor2(p,mq,mn,vfull+(size_t)bid*VSTR+voff(kb+1),
                    Tws+((size_t)bid*NPAN+kb+1)*1024,SM);
    } else {
      int per=30-kb, t=bid-8;
      if(per>0 && t<8*per){
        int b=t/per, cb=t%per;
        blk_update<true>(A+(size_t)b*BSTR, vfull+(size_t)b*VSTR+voff(kb),
                         Tws+((size_t)b*NPAN+kb)*1024, k0, k0+64+(cb<<5), SM);
      }
    }
    grid.sync();
  }

  // orgqr: per kb, form(kb) || right-apply(kb) (disjoint columns)
  for(int kb=NPAN-1;kb>=0;kb--){
    int k0=kb<<5, nu=NPAN-1-kb, ntk=64+8*nu, m=NN-k0;
    for(int task=bid; task<ntk; task+=256){
      if(task<64){
        int b=task>>3, z=task&7;
        form_chunk(A+(size_t)b*BSTR, vfull+(size_t)b*VSTR+voff(kb),
                   Tws+((size_t)b*NPAN+kb)*1024, k0, z, m, SM);
      } else {
        int t2=task-64, b=t2/nu, cb=t2%nu;
        blk_update<false>(A+(size_t)b*BSTR, vfull+(size_t)b*VSTR+voff(kb),
                          Tws+((size_t)b*NPAN+kb)*1024, k0, k0+32+(cb<<5), SM);
      }
    }
    grid.sync();
  }
}

extern "C" void kernel_launch(void* const* d_in, const int* in_sizes, int n_in,
                              void* d_out, int out_size, void* d_ws, size_t ws_size,
                              hipStream_t stream){
  const float* x0=(const float*)d_in[0];
  const int* ei=(const int*)d_in[1];
  int E=in_sizes[1]/2;
  float* out=(float*)d_out;
  float* degF=(float*)d_ws;                      // N
  float* isq =degF+NN;                           // N
  int*  rowoff=(int*)(isq+NN);                   // N+1
  float* Tws  =(float*)d_ws+4096;                // B*32*1024
  float* vfull=Tws+(size_t)BB*NPAN*1024;         // B*VSTR (18.4MB total ws)

  size_t tot=(size_t)BB*NN*DD;
  k_deg_init<<<1,NN,0,stream>>>(degF);
  k_deg<<<(E+255)/256,256,0,stream>>>(ei,degF,E);
  k_scan<<<1,NN,0,stream>>>(degF,isq,rowoff);
  k_copyx0<<<(int)((tot+255)/256),256,0,stream>>>(x0,out);

  for(int l=0;l<LL;l++){
    float* A=out+(size_t)(l+1)*DD;
    k_conv<<<dim3(NN,BB),256,0,stream>>>(out+(size_t)l*DD,ei,degF,isq,rowoff,A);
    void* kargs[]={(void*)&A,(void*)&vfull,(void*)&Tws};
    hipLaunchCooperativeKernel(reinterpret_cast<void*>(k_layer),
                               dim3(256),dim3(512),kargs,0,stream);
  }
}

// Round 10
// 24841.656 us; speedup vs baseline: 3.5039x; 1.2742x over previous
//
#include <hip/hip_runtime.h>
#include <cmath>

#define NN 1024
#define DD 1024
#define BB 8
#define LL 4
#define OUTD (DD*(LL+1))   // 5120
#define NB 32
#define NPAN 32
#define BSTR ((size_t)NN*OUTD)
#define VSTR 540672ull     // per-batch ws floats for V^T dump (sum of 32*m_i)

typedef short b8v __attribute__((ext_vector_type(8)));
typedef float f4v __attribute__((ext_vector_type(4)));
typedef float f4  __attribute__((ext_vector_type(4)));

__device__ __forceinline__ unsigned short f2bf(float x){
  unsigned u=__float_as_uint(x);
  return (unsigned short)((u + 0x7FFFu + ((u>>16)&1u))>>16);
}
__device__ __forceinline__ float bf2f(unsigned short h){
  return __uint_as_float(((unsigned)h)<<16);
}
// 3-split: x = h + m + l -> 6-product MFMA == fp32-equivalent (validated r5-r9)
__device__ __forceinline__ void bsplit3(float x, short& h, short& m, short& l){
  unsigned short hh=f2bf(x);
  float r1=x-bf2f(hh);
  unsigned short mm=f2bf(r1);
  float r2=r1-bf2f(mm);
  h=(short)hh; m=(short)mm; l=(short)f2bf(r2);
}
__device__ __forceinline__ f4v mfma6(b8v ah,b8v am,b8v al,b8v bh,b8v bm,b8v bl,f4v acc){
  acc=__builtin_amdgcn_mfma_f32_16x16x32_bf16(al,bh,acc,0,0,0);
  acc=__builtin_amdgcn_mfma_f32_16x16x32_bf16(ah,bl,acc,0,0,0);
  acc=__builtin_amdgcn_mfma_f32_16x16x32_bf16(am,bm,acc,0,0,0);
  acc=__builtin_amdgcn_mfma_f32_16x16x32_bf16(am,bh,acc,0,0,0);
  acc=__builtin_amdgcn_mfma_f32_16x16x32_bf16(ah,bm,acc,0,0,0);
  acc=__builtin_amdgcn_mfma_f32_16x16x32_bf16(ah,bh,acc,0,0,0);
  return acc;
}
__device__ __forceinline__ size_t voff(int kb){
  return 32768ull*(size_t)kb - 512ull*(size_t)kb*(size_t)(kb-1);
}

// ---- producer/consumer flags (cross-XCD safe: relaxed spin + one fence) ----
__device__ __forceinline__ void wait_flag(int* f){
  if(threadIdx.x==0){
    while(__hip_atomic_load(f, __ATOMIC_RELAXED, __HIP_MEMORY_SCOPE_AGENT)==0)
      __builtin_amdgcn_s_sleep(8);
    __threadfence();   // acquire: one L1/L2 invalidate after flag observed
  }
  __syncthreads();
}
__device__ __forceinline__ void set_flag(int* f){
  __syncthreads();     // all block writes issued + vmcnt-drained
  if(threadIdx.x==0)
    __hip_atomic_store(f, 1, __ATOMIC_RELEASE, __HIP_MEMORY_SCOPE_AGENT);
}

// ---------------- setup ----------------
__global__ void k_init(float* degF, int* flags){
  degF[threadIdx.x]=0.f;
  flags[threadIdx.x]=0;     // 4 layers * 256 flags = 1024
}

__global__ void k_deg(const int* __restrict__ ei, float* __restrict__ degF, int E){
  int e=blockIdx.x*blockDim.x+threadIdx.x;
  if(e<E) atomicAdd(&degF[ei[2*e]],1.f);
}

__global__ void k_scan(const float* __restrict__ degF, float* __restrict__ isq, int* __restrict__ rowoff){
  __shared__ int s[NN];
  int i=threadIdx.x;
  int d=(int)degF[i];
  s[i]=d; __syncthreads();
  for(int off=1;off<NN;off<<=1){
    int v=(i>=off)?s[i-off]:0;
    __syncthreads();
    s[i]+=v;
    __syncthreads();
  }
  if(i==0) rowoff[0]=0;
  rowoff[i+1]=s[i];
  isq[i]=(d>0)?(float)(1.0/sqrt((double)d)):0.f;
}

__global__ void k_copyx0(const float* __restrict__ x0, float* __restrict__ out){
  size_t t=(size_t)blockIdx.x*blockDim.x+threadIdx.x;
  if(t>=(size_t)BB*NN*DD) return;
  int d=(int)(t&(DD-1)); size_t bn=t>>10;
  out[bn*OUTD+d]=x0[t];
}

// ---------------- graph conv ----------------
__global__ void k_conv(const float* __restrict__ xin, const int* __restrict__ ei,
                       const float* __restrict__ degF, const float* __restrict__ isq,
                       const int* __restrict__ rowoff, float* Aout){
  int i=blockIdx.x, b=blockIdx.y;
  __shared__ int sdst[64]; __shared__ float sw[64];
  int r0=rowoff[i], r1=rowoff[i+1];
  int cnt=r1-r0; if(cnt>64) cnt=64;
  float di=degF[i], isqi=isq[i];
  for(int e=threadIdx.x;e<cnt;e+=blockDim.x){
    int dv=ei[2*(r0+e)+1];
    sdst[e]=dv; sw[e]=isqi*isq[dv];
  }
  __syncthreads();
  float cm=((float)(r1-r0))*di/fmaxf(di,1.f);
  const float* xi=xin+((size_t)(b*NN+i))*OUTD;
  float* ao=Aout+((size_t)(b*NN+i))*OUTD;
  for(int d=threadIdx.x; d<DD; d+=blockDim.x){
    float acc=0.f;
    for(int e=0;e<cnt;e++) acc+=sw[e]*xin[((size_t)(b*NN+sdst[e]))*OUTD+d];
    ao[d]=0.5f*acc+0.5f*cm*xi[d];
  }
}

// ---------------- panel factor (r9-verbatim) --------------------------------
__device__ void panel_factor2(float* p, int mq, int m, float* __restrict__ vfT,
                              float* __restrict__ Twslot, char* SM){
  float* vsh2=(float*)SM;                    // 2*1024 f32 (double-buffered v)
  float (*Ssav)[33]=(float(*)[33])(SM+8192); // saved dot vectors
  float* taus=(float*)(SM+12416);            // 32
  int tid=threadIdx.x, c=tid>>4, rw=tid&15;
  #pragma unroll 1
  for(int j=0;j<NB;j++){
    float* vb=vsh2+((j&1)<<10);
    if(c==j){
      float ss=0.f, al=0.f;
      #pragma unroll
      for(int q=0;q<64;q++) if(q<mq){
        int r=rw+(q<<4);
        float pv=p[q];
        if(r>j) ss+=pv*pv; else if(r==j) al=pv;
      }
      #pragma unroll
      for(int o=8;o>0;o>>=1){ ss+=__shfl_xor(ss,o,16); al+=__shfl_xor(al,o,16); }
      float tau,scale;
      if(ss==0.f){ tau=0.f; scale=0.f; }
      else{
        double bn=sqrt((double)al*(double)al+(double)ss);
        float beta=(al>=0.f)?(float)(-bn):(float)bn;   // -sign(alpha)*norm
        tau=(beta-al)/beta; scale=1.f/(al-beta);
      }
      #pragma unroll
      for(int q=0;q<64;q++) if(q<mq){
        int r=rw+(q<<4);
        if(r>j){ p[q]*=scale; vb[r]=p[q]; }
        else if(r==j) vb[r]=1.f;
      }
      if(rw==0) taus[j]=tau;
    }
    __syncthreads();
    float tau=taus[j];
    float sc=0.f;
    #pragma unroll
    for(int q=0;q<64;q++) if(q<mq){
      int r=rw+(q<<4);
      if(r>=j) sc+=vb[r]*p[q];
    }
    #pragma unroll
    for(int o=8;o>0;o>>=1) sc+=__shfl_xor(sc,o,16);
    if(c>j){
      float wv=tau*sc;
      #pragma unroll
      for(int q=0;q<64;q++) if(q<mq){
        int r=rw+(q<<4);
        if(r>=j) p[q]-=wv*vb[r];
      }
    } else if(c<j && rw==0) Ssav[j][c]=sc;
  }
  __syncthreads();
  // T build (parallel; lane rw holds T[c][rw], T[c][rw+16])
  float tq0=0.f,tq1=0.f;
  #pragma unroll
  for(int j=0;j<32;j++){
    float tj=taus[j];
    float s=((rw<j)?tq0*Ssav[j][rw]:0.f)+((rw+16<j)?tq1*Ssav[j][rw+16]:0.f);
    #pragma unroll
    for(int o=8;o>0;o>>=1) s+=__shfl_xor(s,o,16);
    float val=-tj*s;
    if(j>c){ if((j&15)==rw){ if(j<16) tq0=val; else tq1=val; } }
    else if(j==c){ if((j&15)==rw){ if(j<16) tq0=tj; else tq1=tj; } }
  }
  Twslot[(c<<5)+rw]=tq0;
  Twslot[(c<<5)+rw+16]=tq1;
  #pragma unroll
  for(int q=0;q<64;q++) if(q<mq){
    int r=rw+(q<<4);
    vfT[(size_t)c*m+r]=(r>c)?p[q]:((r==c)?1.f:0.f);
  }
  __syncthreads();
}

// ---------------- block reflector apply (r9-verbatim) -----------------------
template<bool TRANS>
__device__ void blk_update(float* __restrict__ Ab, const float* __restrict__ vfT,
                           const float* __restrict__ Tb, int k0, int c0, char* SM){
  float (*Tsh)[33]=(float(*)[33])(SM);              // 4224
  float (*Wt)[33] =(float(*)[33])(SM+4224);         // 4224
  float (*Wp)[32][33]=(float(*)[32][33])(SM+8448);  // 8448 -> 16896
  short (*W2h)[40]=(short(*)[40])(SM+8448);         // aliases Wp (dead by then)
  short (*W2m)[40]=(short(*)[40])(SM+11008);
  short (*W2l)[40]=(short(*)[40])(SM+13568);        // -> 16128
  int tid=threadIdx.x, w=tid>>6, lane=tid&63, lr=lane&15, lq=lane>>4;
  int m=NN-k0;
  for(int idx=tid; idx<1024; idx+=512) Tsh[idx>>5][idx&31]=Tb[idx];
  // ---- pass 1: W = V^T * stripe (K=m) ----
  int jt=w&1, ct=(w>>1)&1, kh=w>>2;
  int ja=jt*16+lr, cb=ct*16+lr;
  int ko=(kh<<5)+(lq<<3);
  f4v acc={0.f,0.f,0.f,0.f};
  for(int rt=0; rt<m; rt+=64){
    int kk=rt+ko;
    float av[8], sv[8];
    if(kk<m){
      *(f4*)&av[0]=*(const f4*)&vfT[(size_t)ja*m+kk];
      *(f4*)&av[4]=*(const f4*)&vfT[(size_t)ja*m+kk+4];
      const float* sp=&Ab[(size_t)(k0+kk)*OUTD + (c0+cb)];
      #pragma unroll
      for(int e=0;e<8;e++) sv[e]=sp[(size_t)e*OUTD];
    } else {
      #pragma unroll
      for(int e=0;e<8;e++){ av[e]=0.f; sv[e]=0.f; }
    }
    b8v ah,am2,al2,bh,bm2,bl2;
    #pragma unroll
    for(int e=0;e<8;e++){
      short h,mi,lo;
      bsplit3(av[e],h,mi,lo); ah[e]=h; am2[e]=mi; al2[e]=lo;
      bsplit3(sv[e],h,mi,lo); bh[e]=h; bm2[e]=mi; bl2[e]=lo;
    }
    acc=mfma6(ah,am2,al2,bh,bm2,bl2,acc);
  }
  // C/D layout: col=lane&15, row=4*(lane>>4)+i [verified m89]
  #pragma unroll
  for(int i=0;i<4;i++) Wp[kh][jt*16+4*lq+i][ct*16+lr]=acc[i];
  __syncthreads();
  #pragma unroll
  for(int s=0;s<2;s++){
    int idx=tid+(s<<9), j=idx>>5, cc=idx&31;
    Wt[j][cc]=Wp[0][j][cc]+Wp[1][j][cc];
  }
  __syncthreads();
  // ---- T apply (f32) ----
  float w2r[2];
  #pragma unroll
  for(int s=0;s<2;s++){
    int idx=tid+(s<<9), cc=idx>>5, j=idx&31;
    float s2=0.f;
    if(TRANS){ for(int q=0;q<=j;q++) s2+=Tsh[q][j]*Wt[q][cc]; }
    else     { for(int q=j;q<32;q++) s2+=Tsh[j][q]*Wt[q][cc]; }
    w2r[s]=s2;
  }
  __syncthreads();   // Wt/Wp reads done -> W2 region free
  #pragma unroll
  for(int s=0;s<2;s++){
    int idx=tid+(s<<9), cc=idx>>5, j=idx&31;
    short h,mi,lo; bsplit3(w2r[s],h,mi,lo);
    W2h[cc][j]=h; W2m[cc][j]=mi; W2l[cc][j]=lo;
  }
  __syncthreads();
  // ---- pass 2: stripe -= V * W2 (K=32) ----
  int rt4=w&3, ct2=w>>2;
  int cb2=ct2*16+lr;
  b8v wh=*(const b8v*)&W2h[cb2][lq<<3];
  b8v wm=*(const b8v*)&W2m[cb2][lq<<3];
  b8v wl=*(const b8v*)&W2l[cb2][lq<<3];
  int ccol=c0+cb2;
  for(int rt=0; rt<m; rt+=64){
    int rbase=rt+rt4*16;
    if(rbase<m){
      float vv[8];
      #pragma unroll
      for(int e=0;e<8;e++) vv[e]=vfT[(size_t)(8*lq+e)*m + rbase+lr];
      b8v ah,am2,al2;
      #pragma unroll
      for(int e=0;e<8;e++){ short h,mi,lo; bsplit3(vv[e],h,mi,lo); ah[e]=h; am2[e]=mi; al2[e]=lo; }
      f4v a2={0.f,0.f,0.f,0.f};
      a2=mfma6(ah,am2,al2,wh,wm,wl,a2);
      #pragma unroll
      for(int i=0;i<4;i++){
        int r=rbase+4*lq+i;
        Ab[(size_t)(k0+r)*OUTD+ccol]-=a2[i];
      }
    }
  }
  __syncthreads();
}

// ---------------- Q-panel formation, one 128-row chunk (r9-verbatim) --------
__device__ void form_chunk(float* __restrict__ Ab, const float* __restrict__ vfT,
                           const float* __restrict__ Tb, int k0, int z, int m, char* SM){
  float (*Tsh)[33]=(float(*)[33])(SM);
  float (*Vtf)[33]=(float(*)[33])(SM+4224);   // V^T top: Vtf[j][i]=V[i][j]
  float (*Sf)[33] =(float(*)[33])(SM+8448);
  int tid=threadIdx.x;
  for(int idx=tid; idx<1024; idx+=512){
    int j=idx>>5, i=idx&31;
    Tsh[j][i]=Tb[idx];
    Vtf[j][i]=vfT[(size_t)j*m+i];
  }
  __syncthreads();
  for(int idx=tid; idx<1024; idx+=512){
    int q=idx>>5, cc=idx&31;
    float s=0.f;
    for(int pp2=q;pp2<32;pp2++) s+=Tsh[q][pp2]*Vtf[pp2][cc];
    Sf[q][cc]=s;
  }
  __syncthreads();
  int c2=tid&31, rg=tid>>5;
  for(int rr=rg; rr<128; rr+=16){
    int r=(z<<7)+rr;
    float outv;
    if(r<k0) outv=0.f;
    else{
      int rl=r-k0;
      float s=0.f;
      #pragma unroll
      for(int q=0;q<32;q++) s+=vfT[(size_t)q*m+rl]*Sf[q][c2];
      outv=((rl==c2)?1.f:0.f)-s;
    }
    Ab[(size_t)r*OUTD+k0+c2]=outv;
  }
  __syncthreads();
}

// ---------------- DAG per-layer QR: block (b,j) owns col-group j of batch b --
// geqrf: apply kb=0..j-1 (flag-gated) to own cols, factor panel j, publish.
// orgqr: form own Q cols, then apply kb=j-1..0 descending (all flags already
// consumed). No other block ever touches cols j of A -> race-free, 0 barriers.
__global__ __launch_bounds__(512) void k_layer(float* A, float* vfull, float* Tws, int* flags){
  __shared__ __align__(16) char SM[16896];
  int bid=blockIdx.x, tid=threadIdx.x;
  int b=bid>>5, j=bid&31;
  float* Ab=A+(size_t)b*BSTR;
  float* vfb=vfull+(size_t)b*VSTR;
  float* Tb =Tws+(size_t)b*NPAN*1024;
  int* fb=flags+(b<<5);
  int c0=j<<5;
  int c=tid>>4, rw=tid&15;

  // ---- geqrf chain ----
  for(int kb=0; kb<j; kb++){
    wait_flag(&fb[kb]);
    blk_update<true>(Ab, vfb+voff(kb), Tb+(size_t)kb*1024, kb<<5, c0, SM);
  }
  {
    int m=NN-c0, mq=m>>4;
    float p[64];
    #pragma unroll
    for(int q=0;q<64;q++){
      p[q]=0.f;
      if(q<mq){ int r=rw+(q<<4); p[q]=Ab[(size_t)(c0+r)*OUTD+c0+c]; }
    }
    panel_factor2(p,mq,m,vfb+voff(j),Tb+(size_t)j*1024,SM);
    set_flag(&fb[j]);
  }
  // ---- orgqr for own stripe ----
  {
    int m=NN-c0;
    for(int z=0;z<8;z++)
      form_chunk(Ab, vfb+voff(j), Tb+(size_t)j*1024, c0, z, m, SM);
  }
  for(int kb=j-1; kb>=0; kb--)
    blk_update<false>(Ab, vfb+voff(kb), Tb+(size_t)kb*1024, kb<<5, c0, SM);
}

extern "C" void kernel_launch(void* const* d_in, const int* in_sizes, int n_in,
                              void* d_out, int out_size, void* d_ws, size_t ws_size,
                              hipStream_t stream){
  const float* x0=(const float*)d_in[0];
  const int* ei=(const int*)d_in[1];
  int E=in_sizes[1]/2;
  float* out=(float*)d_out;
  float* degF=(float*)d_ws;                      // N
  float* isq =degF+NN;                           // N
  int*  rowoff=(int*)(isq+NN);                   // N+1
  float* Tws  =(float*)d_ws+4096;                // B*32*1024
  float* vfull=Tws+(size_t)BB*NPAN*1024;         // B*VSTR
  int*  flags =(int*)(vfull+(size_t)BB*VSTR);    // 4 layers * 256  (~18.4MB total)

  size_t tot=(size_t)BB*NN*DD;
  k_init<<<1,1024,0,stream>>>(degF,flags);
  k_deg<<<(E+255)/256,256,0,stream>>>(ei,degF,E);
  k_scan<<<1,NN,0,stream>>>(degF,isq,rowoff);
  k_copyx0<<<(int)((tot+255)/256),256,0,stream>>>(x0,out);

  for(int l=0;l<LL;l++){
    float* A=out+(size_t)(l+1)*DD;
    k_conv<<<dim3(NN,BB),256,0,stream>>>(out+(size_t)l*DD,ei,degF,isq,rowoff,A);
    int* fl=flags+l*256;
    void* kargs[]={(void*)&A,(void*)&vfull,(void*)&Tws,(void*)&fl};
    hipLaunchCooperativeKernel(reinterpret_cast<void*>(k_layer),
                               dim3(256),dim3(512),kargs,0,stream);
  }
}

// Round 11
// 15787.352 us; speedup vs baseline: 5.5135x; 1.5735x over previous
//
#include <hip/hip_runtime.h>
#include <cmath>

#define NN 1024
#define DD 1024
#define BB 8
#define LL 4
#define OUTD (DD*(LL+1))   // 5120
#define NB 32
#define NPAN 32
#define BSTR ((size_t)NN*OUTD)
#define VSTR 540672ull     // per-batch elements of V^T dump (sum of 32*m_i)

typedef short b8v __attribute__((ext_vector_type(8)));
typedef float f4v __attribute__((ext_vector_type(4)));

__device__ __forceinline__ unsigned short f2bf(float x){
  unsigned u=__float_as_uint(x);
  return (unsigned short)((u + 0x7FFFu + ((u>>16)&1u))>>16);
}
__device__ __forceinline__ float bf2f(unsigned short h){
  return __uint_as_float(((unsigned)h)<<16);
}
// 3-split: x = h + m + l -> 6-product MFMA == fp32-equivalent (validated r5-r10)
__device__ __forceinline__ void bsplit3(float x, short& h, short& m, short& l){
  unsigned short hh=f2bf(x);
  float r1=x-bf2f(hh);
  unsigned short mm=f2bf(r1);
  float r2=r1-bf2f(mm);
  h=(short)hh; m=(short)mm; l=(short)f2bf(r2);
}
__device__ __forceinline__ f4v mfma6(b8v ah,b8v am,b8v al,b8v bh,b8v bm,b8v bl,f4v acc){
  acc=__builtin_amdgcn_mfma_f32_16x16x32_bf16(al,bh,acc,0,0,0);
  acc=__builtin_amdgcn_mfma_f32_16x16x32_bf16(ah,bl,acc,0,0,0);
  acc=__builtin_amdgcn_mfma_f32_16x16x32_bf16(am,bm,acc,0,0,0);
  acc=__builtin_amdgcn_mfma_f32_16x16x32_bf16(am,bh,acc,0,0,0);
  acc=__builtin_amdgcn_mfma_f32_16x16x32_bf16(ah,bm,acc,0,0,0);
  acc=__builtin_amdgcn_mfma_f32_16x16x32_bf16(ah,bh,acc,0,0,0);
  return acc;
}
__device__ __forceinline__ size_t voff(int kb){
  return 32768ull*(size_t)kb - 512ull*(size_t)kb*(size_t)(kb-1);
}

// ---- producer/consumer flags (protocol validated r10: passed both checks) --
__device__ __forceinline__ void wait_flag(int* f){
  if(threadIdx.x==0){
    while(__hip_atomic_load(f, __ATOMIC_RELAXED, __HIP_MEMORY_SCOPE_AGENT)==0)
      __builtin_amdgcn_s_sleep(8);
    __threadfence();
  }
  __syncthreads();
}
__device__ __forceinline__ void set_flag(int* f){
  __syncthreads();
  if(threadIdx.x==0)
    __hip_atomic_store(f, 1, __ATOMIC_RELEASE, __HIP_MEMORY_SCOPE_AGENT);
}

// ---------------- setup ----------------
__global__ void k_init(float* degF, int* flags){
  degF[threadIdx.x]=0.f;
  flags[threadIdx.x]=0;     // 4 layers * 256 flags
}

__global__ void k_deg(const int* __restrict__ ei, float* __restrict__ degF, int E){
  int e=blockIdx.x*blockDim.x+threadIdx.x;
  if(e<E) atomicAdd(&degF[ei[2*e]],1.f);
}

__global__ void k_scan(const float* __restrict__ degF, float* __restrict__ isq, int* __restrict__ rowoff){
  __shared__ int s[NN];
  int i=threadIdx.x;
  int d=(int)degF[i];
  s[i]=d; __syncthreads();
  for(int off=1;off<NN;off<<=1){
    int v=(i>=off)?s[i-off]:0;
    __syncthreads();
    s[i]+=v;
    __syncthreads();
  }
  if(i==0) rowoff[0]=0;
  rowoff[i+1]=s[i];
  isq[i]=(d>0)?(float)(1.0/sqrt((double)d)):0.f;
}

__global__ void k_copyx0(const float* __restrict__ x0, float* __restrict__ out){
  size_t t=(size_t)blockIdx.x*blockDim.x+threadIdx.x;
  if(t>=(size_t)BB*NN*DD) return;
  int d=(int)(t&(DD-1)); size_t bn=t>>10;
  out[bn*OUTD+d]=x0[t];
}

// ---------------- graph conv ----------------
__global__ void k_conv(const float* __restrict__ xin, const int* __restrict__ ei,
                       const float* __restrict__ degF, const float* __restrict__ isq,
                       const int* __restrict__ rowoff, float* Aout){
  int i=blockIdx.x, b=blockIdx.y;
  __shared__ int sdst[64]; __shared__ float sw[64];
  int r0=rowoff[i], r1=rowoff[i+1];
  int cnt=r1-r0; if(cnt>64) cnt=64;
  float di=degF[i], isqi=isq[i];
  for(int e=threadIdx.x;e<cnt;e+=blockDim.x){
    int dv=ei[2*(r0+e)+1];
    sdst[e]=dv; sw[e]=isqi*isq[dv];
  }
  __syncthreads();
  float cm=((float)(r1-r0))*di/fmaxf(di,1.f);
  const float* xi=xin+((size_t)(b*NN+i))*OUTD;
  float* ao=Aout+((size_t)(b*NN+i))*OUTD;
  for(int d=threadIdx.x; d<DD; d+=blockDim.x){
    float acc=0.f;
    for(int e=0;e<cnt;e++) acc+=sw[e]*xin[((size_t)(b*NN+sdst[e]))*OUTD+d];
    ao[d]=0.5f*acc+0.5f*cm*xi[d];
  }
}

// ---------------- panel factor: register-resident via forced inline ---------
// MQ = compile-time max owned rows per thread; p stays in VGPRs (SROA).
template<int MQ>
__device__ __forceinline__ void panel_factor2(float (&p)[MQ], int mq, int m,
    short* __restrict__ vh, short* __restrict__ vm2, short* __restrict__ vl,
    float* __restrict__ Twslot, char* SM){
  float* vsh2=(float*)SM;                    // 2*1024 f32 (double-buffered v)
  float (*Ssav)[33]=(float(*)[33])(SM+8192);
  float* taus=(float*)(SM+12416);
  int tid=threadIdx.x, c=tid>>4, rw=tid&15;
  #pragma unroll 1
  for(int j=0;j<NB;j++){
    float* vb=vsh2+((j&1)<<10);
    if(c==j){
      float ss=0.f, al=0.f;
      #pragma unroll
      for(int q=0;q<MQ;q++) if(q<mq){
        int r=rw+(q<<4);
        float pv=p[q];
        if(r>j) ss+=pv*pv; else if(r==j) al=pv;
      }
      #pragma unroll
      for(int o=8;o>0;o>>=1){ ss+=__shfl_xor(ss,o,16); al+=__shfl_xor(al,o,16); }
      float tau,scale;
      if(ss==0.f){ tau=0.f; scale=0.f; }
      else{
        double bn=sqrt((double)al*(double)al+(double)ss);
        float beta=(al>=0.f)?(float)(-bn):(float)bn;   // -sign(alpha)*norm
        tau=(beta-al)/beta; scale=1.f/(al-beta);
      }
      #pragma unroll
      for(int q=0;q<MQ;q++) if(q<mq){
        int r=rw+(q<<4);
        if(r>j){ p[q]*=scale; vb[r]=p[q]; }
        else if(r==j) vb[r]=1.f;
      }
      if(rw==0) taus[j]=tau;
    }
    __syncthreads();
    float tau=taus[j];
    float sc=0.f;
    #pragma unroll
    for(int q=0;q<MQ;q++) if(q<mq){
      int r=rw+(q<<4);
      if(r>=j) sc+=vb[r]*p[q];
    }
    #pragma unroll
    for(int o=8;o>0;o>>=1) sc+=__shfl_xor(sc,o,16);
    if(c>j){
      float wv=tau*sc;
      #pragma unroll
      for(int q=0;q<MQ;q++) if(q<mq){
        int r=rw+(q<<4);
        if(r>=j) p[q]-=wv*vb[r];
      }
    } else if(c<j && rw==0) Ssav[j][c]=sc;
  }
  __syncthreads();
  // T build (parallel; lane rw holds T[c][rw], T[c][rw+16])
  float tq0=0.f,tq1=0.f;
  #pragma unroll
  for(int j=0;j<32;j++){
    float tj=taus[j];
    float s=((rw<j)?tq0*Ssav[j][rw]:0.f)+((rw+16<j)?tq1*Ssav[j][rw+16]:0.f);
    #pragma unroll
    for(int o=8;o>0;o>>=1) s+=__shfl_xor(s,o,16);
    float val=-tj*s;
    if(j>c){ if((j&15)==rw){ if(j<16) tq0=val; else tq1=val; } }
    else if(j==c){ if((j&15)==rw){ if(j<16) tq0=tj; else tq1=tj; } }
  }
  Twslot[(c<<5)+rw]=tq0;
  Twslot[(c<<5)+rw+16]=tq1;
  // split writeback of V^T (bsplit once; updates load b8v directly)
  #pragma unroll
  for(int q=0;q<MQ;q++) if(q<mq){
    int r=rw+(q<<4);
    float v=(r>c)?p[q]:((r==c)?1.f:0.f);
    short h,mi,lo; bsplit3(v,h,mi,lo);
    size_t o2=(size_t)c*m+r;
    vh[o2]=h; vm2[o2]=mi; vl[o2]=lo;
  }
  __syncthreads();
}

template<int MQ>
__device__ __forceinline__ void panel_phase(float* __restrict__ Ab, int c0, int m,
    short* __restrict__ vh, short* __restrict__ vm2, short* __restrict__ vl,
    float* __restrict__ Tw, char* SM){
  int tid=threadIdx.x, c=tid>>4, rw=tid&15;
  int mq=m>>4;
  float p[MQ];
  #pragma unroll
  for(int q=0;q<MQ;q++){
    p[q]=0.f;
    if(q<mq){ int r=rw+(q<<4); p[q]=Ab[(size_t)(c0+r)*OUTD+c0+c]; }
  }
  panel_factor2<MQ>(p,mq,m,vh,vm2,vl,Tw,SM);
}

// ---------------- block reflector apply: pre-split V + prefetch -------------
// TRANS=true : cols <- (I - V T^T V^T) cols   (geqrf)
// TRANS=false: cols <- (I - V T   V^T) cols   (orgqr)
template<bool TRANS>
__device__ void blk_update(float* __restrict__ Ab,
    const short* __restrict__ vh, const short* __restrict__ vm2, const short* __restrict__ vl,
    const float* __restrict__ Tb, int k0, int c0, char* SM){
  float (*Tsh)[33]=(float(*)[33])(SM);              // 4224
  float (*Wt)[33] =(float(*)[33])(SM+4224);         // 4224
  float (*Wp)[32][33]=(float(*)[32][33])(SM+8448);  // 8448 -> 16896
  short (*W2h)[40]=(short(*)[40])(SM+8448);         // aliases Wp (dead by then)
  short (*W2m)[40]=(short(*)[40])(SM+11008);
  short (*W2l)[40]=(short(*)[40])(SM+13568);
  int tid=threadIdx.x, w=tid>>6, lane=tid&63, lr=lane&15, lq=lane>>4;
  int m=NN-k0;
  for(int idx=tid; idx<1024; idx+=512) Tsh[idx>>5][idx&31]=Tb[idx];
  // ---- pass 1: W = V^T * stripe (K=m), prefetched ----
  int jt=w&1, ct=(w>>1)&1, kh=w>>2;
  int ja=jt*16+lr, cb=ct*16+lr;
  int ko=(kh<<5)+(lq<<3);
  const short* ph=vh +(size_t)ja*m;
  const short* pm=vm2+(size_t)ja*m;
  const short* pl=vl +(size_t)ja*m;
  const float* sp0=Ab+(size_t)k0*OUTD + c0+cb;
  f4v acc={0.f,0.f,0.f,0.f};
  const b8v zz={0,0,0,0,0,0,0,0};
  b8v ah=zz,amv=zz,alv=zz; float sv[8];
  #pragma unroll
  for(int e=0;e<8;e++) sv[e]=0.f;
  if(ko<m){
    ah=*(const b8v*)(ph+ko); amv=*(const b8v*)(pm+ko); alv=*(const b8v*)(pl+ko);
    const float* sp=sp0+(size_t)ko*OUTD;
    #pragma unroll
    for(int e=0;e<8;e++) sv[e]=sp[(size_t)e*OUTD];
  }
  for(int rt=0; rt<m; rt+=64){
    b8v nh=zz,nm=zz,nl=zz; float nsv[8];
    #pragma unroll
    for(int e=0;e<8;e++) nsv[e]=0.f;
    int nk=rt+64+ko;
    if(nk<m){
      nh=*(const b8v*)(ph+nk); nm=*(const b8v*)(pm+nk); nl=*(const b8v*)(pl+nk);
      const float* sp=sp0+(size_t)nk*OUTD;
      #pragma unroll
      for(int e=0;e<8;e++) nsv[e]=sp[(size_t)e*OUTD];
    }
    b8v bh,bm2,bl2;
    #pragma unroll
    for(int e=0;e<8;e++){ short h,mi,lo; bsplit3(sv[e],h,mi,lo); bh[e]=h; bm2[e]=mi; bl2[e]=lo; }
    acc=mfma6(ah,amv,alv,bh,bm2,bl2,acc);
    ah=nh; amv=nm; alv=nl;
    #pragma unroll
    for(int e=0;e<8;e++) sv[e]=nsv[e];
  }
  // C/D layout: col=lane&15, row=4*(lane>>4)+i [verified m89]
  #pragma unroll
  for(int i=0;i<4;i++) Wp[kh][jt*16+4*lq+i][ct*16+lr]=acc[i];
  __syncthreads();
  #pragma unroll
  for(int s=0;s<2;s++){
    int idx=tid+(s<<9), j=idx>>5, cc=idx&31;
    Wt[j][cc]=Wp[0][j][cc]+Wp[1][j][cc];
  }
  __syncthreads();
  // ---- T apply (f32) ----
  float w2r[2];
  #pragma unroll
  for(int s=0;s<2;s++){
    int idx=tid+(s<<9), cc=idx>>5, j=idx&31;
    float s2=0.f;
    if(TRANS){ for(int q=0;q<=j;q++) s2+=Tsh[q][j]*Wt[q][cc]; }
    else     { for(int q=j;q<32;q++) s2+=Tsh[j][q]*Wt[q][cc]; }
    w2r[s]=s2;
  }
  __syncthreads();   // Wt/Wp reads done -> W2 region free
  #pragma unroll
  for(int s=0;s<2;s++){
    int idx=tid+(s<<9), cc=idx>>5, j=idx&31;
    short h,mi,lo; bsplit3(w2r[s],h,mi,lo);
    W2h[cc][j]=h; W2m[cc][j]=mi; W2l[cc][j]=lo;
  }
  __syncthreads();
  // ---- pass 2: stripe -= V * W2 (K=32) ----
  int rt4=w&3, ct2=w>>2;
  int cb2=ct2*16+lr;
  b8v wh=*(const b8v*)&W2h[cb2][lq<<3];
  b8v wm=*(const b8v*)&W2m[cb2][lq<<3];
  b8v wl2=*(const b8v*)&W2l[cb2][lq<<3];
  int ccol=c0+cb2;
  for(int rt=0; rt<m; rt+=64){
    int rbase=rt+rt4*16;
    if(rbase<m){
      float oldv[4];
      #pragma unroll
      for(int i=0;i<4;i++) oldv[i]=Ab[(size_t)(k0+rbase+4*lq+i)*OUTD+ccol];
      b8v ah2,am3,al3;
      #pragma unroll
      for(int e=0;e<8;e++){
        size_t o2=(size_t)(8*lq+e)*m + rbase+lr;
        ah2[e]=vh[o2]; am3[e]=vm2[o2]; al3[e]=vl[o2];
      }
      f4v a2={0.f,0.f,0.f,0.f};
      a2=mfma6(ah2,am3,al3,wh,wm,wl2,a2);
      #pragma unroll
      for(int i=0;i<4;i++)
        Ab[(size_t)(k0+rbase+4*lq+i)*OUTD+ccol]=oldv[i]-a2[i];
    }
  }
  __syncthreads();
}

// ---------------- DAG per-layer QR: block (b,j) owns col-group j -------------
// geqrf: flag-gated updates kb<j, factor panel j, publish.
// orgqr: stripe <- E_j, then updates kb=j..0 (all V/T already published).
__global__ __launch_bounds__(512) void k_layer(float* A, short* vTh, short* vTm, short* vTl,
                                               float* Tws, int* flags){
  __shared__ __align__(16) char SM[16896];
  int bid=blockIdx.x, tid=threadIdx.x;
  int b=bid>>5, j=bid&31;
  float* Ab=A+(size_t)b*BSTR;
  short* vhb=vTh+(size_t)b*VSTR;
  short* vmb=vTm+(size_t)b*VSTR;
  short* vlb=vTl+(size_t)b*VSTR;
  float* Tb =Tws+(size_t)b*NPAN*1024;
  int* fb=flags+(b<<5);
  int c0=j<<5;

  // ---- geqrf chain ----
  for(int kb=0; kb<j; kb++){
    wait_flag(&fb[kb]);
    size_t vo=voff(kb);
    blk_update<true>(Ab, vhb+vo, vmb+vo, vlb+vo, Tb+(size_t)kb*1024, kb<<5, c0, SM);
  }
  {
    int m=NN-c0;
    size_t vo=voff(j);
    float* Tw=Tb+(size_t)j*1024;
    if(j<8)       panel_phase<64>(Ab,c0,m, vhb+vo,vmb+vo,vlb+vo, Tw, SM);
    else if(j<16) panel_phase<48>(Ab,c0,m, vhb+vo,vmb+vo,vlb+vo, Tw, SM);
    else if(j<24) panel_phase<32>(Ab,c0,m, vhb+vo,vmb+vo,vlb+vo, Tw, SM);
    else          panel_phase<16>(Ab,c0,m, vhb+vo,vmb+vo,vlb+vo, Tw, SM);
    set_flag(&fb[j]);
  }
  // ---- orgqr: stripe <- E_j, then descending applies ----
  for(int idx=tid; idx<NN*32; idx+=512){
    int r=idx>>5, cc=idx&31;
    Ab[(size_t)r*OUTD+c0+cc]=(r==c0+cc)?1.f:0.f;
  }
  __syncthreads();
  for(int kb=j; kb>=0; kb--){
    size_t vo=voff(kb);
    blk_update<false>(Ab, vhb+vo, vmb+vo, vlb+vo, Tb+(size_t)kb*1024, kb<<5, c0, SM);
  }
}

extern "C" void kernel_launch(void* const* d_in, const int* in_sizes, int n_in,
                              void* d_out, int out_size, void* d_ws, size_t ws_size,
                              hipStream_t stream){
  const float* x0=(const float*)d_in[0];
  const int* ei=(const int*)d_in[1];
  int E=in_sizes[1]/2;
  float* out=(float*)d_out;
  // ws layout (~27.0 MB total)
  float* W=(float*)d_ws;
  float* degF=W;                         // 1024
  float* isq =W+1024;                    // 1024
  int*  rowoff=(int*)(W+2048);           // 1025
  int*  flags =(int*)(W+2048)+1040;      // 1024
  float* Tws  =W+4352;                   // 8*32*1024 = 262144
  short* vTh  =(short*)(Tws+262144);     // 8*VSTR shorts
  short* vTm  =vTh+(size_t)BB*VSTR;
  short* vTl  =vTm+(size_t)BB*VSTR;

  size_t tot=(size_t)BB*NN*DD;
  k_init<<<1,1024,0,stream>>>(degF,flags);
  k_deg<<<(E+255)/256,256,0,stream>>>(ei,degF,E);
  k_scan<<<1,NN,0,stream>>>(degF,isq,rowoff);
  k_copyx0<<<(int)((tot+255)/256),256,0,stream>>>(x0,out);

  for(int l=0;l<LL;l++){
    float* A=out+(size_t)(l+1)*DD;
    k_conv<<<dim3(NN,BB),256,0,stream>>>(out+(size_t)l*DD,ei,degF,isq,rowoff,A);
    int* fl=flags+l*256;
    void* kargs[]={(void*)&A,(void*)&vTh,(void*)&vTm,(void*)&vTl,(void*)&Tws,(void*)&fl};
    hipLaunchCooperativeKernel(reinterpret_cast<void*>(k_layer),
                               dim3(256),dim3(512),kargs,0,stream);
  }
}

// Round 12
// 14828.468 us; speedup vs baseline: 5.8700x; 1.0647x over previous
//
#include <hip/hip_runtime.h>
#include <hip/hip_cooperative_groups.h>
#include <cmath>

namespace cg = cooperative_groups;

#define NN 1024
#define BB 8
#define LL 4
#define OUTD 5120
#define NB 32
#define VSTR 540672ull     // per-batch elements of V^T dump (sum of 32*m_i)
#define SMBYTES 152064     // 1024*33*4 (stripe) + 16896 (scratch)

typedef short b8v __attribute__((ext_vector_type(8)));
typedef float f4v __attribute__((ext_vector_type(4)));

__device__ __forceinline__ unsigned short f2bf(float x){
  unsigned u=__float_as_uint(x);
  return (unsigned short)((u + 0x7FFFu + ((u>>16)&1u))>>16);
}
__device__ __forceinline__ float bf2f(unsigned short h){
  return __uint_as_float(((unsigned)h)<<16);
}
// 3-split: x=h+m+l -> 6-product MFMA == fp32-equivalent (validated r5-r11)
__device__ __forceinline__ void bsplit3(float x, short& h, short& m, short& l){
  unsigned short hh=f2bf(x);
  float r1=x-bf2f(hh);
  unsigned short mm=f2bf(r1);
  float r2=r1-bf2f(mm);
  h=(short)hh; m=(short)mm; l=(short)f2bf(r2);
}
__device__ __forceinline__ f4v mfma6(b8v ah,b8v am,b8v al,b8v bh,b8v bm,b8v bl,f4v acc){
  acc=__builtin_amdgcn_mfma_f32_16x16x32_bf16(al,bh,acc,0,0,0);
  acc=__builtin_amdgcn_mfma_f32_16x16x32_bf16(ah,bl,acc,0,0,0);
  acc=__builtin_amdgcn_mfma_f32_16x16x32_bf16(am,bm,acc,0,0,0);
  acc=__builtin_amdgcn_mfma_f32_16x16x32_bf16(am,bh,acc,0,0,0);
  acc=__builtin_amdgcn_mfma_f32_16x16x32_bf16(ah,bm,acc,0,0,0);
  acc=__builtin_amdgcn_mfma_f32_16x16x32_bf16(ah,bh,acc,0,0,0);
  return acc;
}
__device__ __forceinline__ size_t voff(int kb){
  return 32768ull*(size_t)kb - 512ull*(size_t)kb*(size_t)(kb-1);
}

// ---- flags (protocol validated r10/r11) ----
__device__ __forceinline__ void wait_flag(int* f){
  if(threadIdx.x==0){
    while(__hip_atomic_load(f, __ATOMIC_RELAXED, __HIP_MEMORY_SCOPE_AGENT)==0)
      __builtin_amdgcn_s_sleep(8);
    __threadfence();
  }
  __syncthreads();
}
__device__ __forceinline__ void set_flag(int* f){
  __syncthreads();
  if(threadIdx.x==0)
    __hip_atomic_store(f, 1, __ATOMIC_RELEASE, __HIP_MEMORY_SCOPE_AGENT);
}

// ---------------- setup ----------------
__global__ void k_init(float* degF, int* flags){
  degF[threadIdx.x]=0.f;
  flags[threadIdx.x]=0;     // LL*BB*32 = 1024
}
__global__ void k_deg(const int* __restrict__ ei, float* __restrict__ degF, int E){
  int e=blockIdx.x*blockDim.x+threadIdx.x;
  if(e<E) atomicAdd(&degF[ei[2*e]],1.f);
}
__global__ void k_scan(const float* __restrict__ degF, float* __restrict__ isq, int* __restrict__ rowoff){
  __shared__ int s[NN];
  int i=threadIdx.x;
  int d=(int)degF[i];
  s[i]=d; __syncthreads();
  for(int off=1;off<NN;off<<=1){
    int v=(i>=off)?s[i-off]:0;
    __syncthreads();
    s[i]+=v;
    __syncthreads();
  }
  if(i==0) rowoff[0]=0;
  rowoff[i+1]=s[i];
  isq[i]=(d>0)?(float)(1.0/sqrt((double)d)):0.f;
}
__global__ void k_sw(const int* __restrict__ ei, const float* __restrict__ isq,
                     float* __restrict__ swv, int E){
  int e=blockIdx.x*blockDim.x+threadIdx.x;
  if(e<E) swv[e]=isq[ei[2*e]]*isq[ei[2*e+1]];
}

// ---------------- conv on LDS-resident stripe -------------------------------
__device__ void conv_S(float (*S)[33], const int* __restrict__ ei,
                       const float* __restrict__ swv, const float* __restrict__ degF,
                       const int* __restrict__ rowoff){
  int tid=threadIdx.x;
  int ra=2*tid, rb=2*tid+1;
  int e0=rowoff[ra], e1=rowoff[rb], e2=rowoff[rb+1];
  float a0[32], a1[32];
  #pragma unroll
  for(int c=0;c<32;c++){ a0[c]=0.f; a1[c]=0.f; }
  for(int e=e0;e<e1;e++){
    int dv=ei[2*e+1]; float w=swv[e];
    #pragma unroll
    for(int c=0;c<32;c++) a0[c]+=w*S[dv][c];
  }
  for(int e=e1;e<e2;e++){
    int dv=ei[2*e+1]; float w=swv[e];
    #pragma unroll
    for(int c=0;c<32;c++) a1[c]+=w*S[dv][c];
  }
  float d0=degF[ra], d1=degF[rb];
  float cm0=(float)(e1-e0)*d0/fmaxf(d0,1.f);
  float cm1=(float)(e2-e1)*d1/fmaxf(d1,1.f);
  #pragma unroll
  for(int c=0;c<32;c++){
    a0[c]=0.5f*a0[c]+0.5f*cm0*S[ra][c];
    a1[c]=0.5f*a1[c]+0.5f*cm1*S[rb][c];
  }
  __syncthreads();
  #pragma unroll
  for(int c=0;c<32;c++){ S[ra][c]=a0[c]; S[rb][c]=a1[c]; }
  __syncthreads();
}

// ---------------- block reflector apply on LDS stripe -----------------------
// TRANS=true : S <- (I - V T^T V^T) S   (geqrf);  false: orgqr form
template<bool TRANS>
__device__ void apply_S(float (*S)[33], char* SC,
    const short* __restrict__ vh, const short* __restrict__ vm2, const short* __restrict__ vl,
    const float* __restrict__ Tb, int k0){
  float (*Tsh)[33]=(float(*)[33])(SC);              // 4224
  float (*Wt)[33] =(float(*)[33])(SC+4224);         // 4224
  float (*Wp)[32][33]=(float(*)[32][33])(SC+8448);  // 8448
  short (*W2h)[40]=(short(*)[40])(SC+8448);         // aliases Wp (dead by then)
  short (*W2m)[40]=(short(*)[40])(SC+11008);
  short (*W2l)[40]=(short(*)[40])(SC+13568);
  int tid=threadIdx.x, w=tid>>6, lane=tid&63, lr=lane&15, lq=lane>>4;
  int m=NN-k0;
  for(int idx=tid; idx<1024; idx+=512) Tsh[idx>>5][idx&31]=Tb[idx];
  // ---- pass 1: W = V^T * S (K=m) ----
  int jt=w&1, ct=(w>>1)&1, kh=w>>2;
  int ja=jt*16+lr, cb=ct*16+lr;
  int ko=(kh<<5)+(lq<<3);
  const short* ph=vh +(size_t)ja*m;
  const short* pm=vm2+(size_t)ja*m;
  const short* pl=vl +(size_t)ja*m;
  f4v acc={0.f,0.f,0.f,0.f};
  const b8v zz={0,0,0,0,0,0,0,0};
  b8v ah=zz,amv=zz,alv=zz;
  if(ko<m){ ah=*(const b8v*)(ph+ko); amv=*(const b8v*)(pm+ko); alv=*(const b8v*)(pl+ko); }
  for(int rt=0; rt<m; rt+=64){
    int kk=rt+ko;
    b8v nh=zz,nm=zz,nl=zz;
    int nk=kk+64;
    if(nk<m){ nh=*(const b8v*)(ph+nk); nm=*(const b8v*)(pm+nk); nl=*(const b8v*)(pl+nk); }
    float sv[8];
    if(kk<m){
      #pragma unroll
      for(int e=0;e<8;e++) sv[e]=S[k0+kk+e][cb];
    } else {
      #pragma unroll
      for(int e=0;e<8;e++) sv[e]=0.f;
    }
    b8v bh,bm2,bl2;
    #pragma unroll
    for(int e=0;e<8;e++){ short h,mi,lo; bsplit3(sv[e],h,mi,lo); bh[e]=h; bm2[e]=mi; bl2[e]=lo; }
    acc=mfma6(ah,amv,alv,bh,bm2,bl2,acc);
    ah=nh; amv=nm; alv=nl;
  }
  // C/D layout: col=lane&15, row=4*(lane>>4)+i [verified m89]
  #pragma unroll
  for(int i=0;i<4;i++) Wp[kh][jt*16+4*lq+i][ct*16+lr]=acc[i];
  __syncthreads();
  #pragma unroll
  for(int s=0;s<2;s++){
    int idx=tid+(s<<9), j=idx>>5, cc=idx&31;
    Wt[j][cc]=Wp[0][j][cc]+Wp[1][j][cc];
  }
  __syncthreads();
  // ---- T apply (f32) ----
  float w2r[2];
  #pragma unroll
  for(int s=0;s<2;s++){
    int idx=tid+(s<<9), cc=idx>>5, j=idx&31;
    float s2=0.f;
    if(TRANS){ for(int q=0;q<=j;q++) s2+=Tsh[q][j]*Wt[q][cc]; }
    else     { for(int q=j;q<32;q++) s2+=Tsh[j][q]*Wt[q][cc]; }
    w2r[s]=s2;
  }
  __syncthreads();
  #pragma unroll
  for(int s=0;s<2;s++){
    int idx=tid+(s<<9), cc=idx>>5, j=idx&31;
    short h,mi,lo; bsplit3(w2r[s],h,mi,lo);
    W2h[cc][j]=h; W2m[cc][j]=mi; W2l[cc][j]=lo;
  }
  __syncthreads();
  // ---- pass 2: S -= V * W2 (K=32) ----
  int rt4=w&3, ct2=w>>2;
  int cb2=ct2*16+lr;
  b8v wh=*(const b8v*)&W2h[cb2][lq<<3];
  b8v wm=*(const b8v*)&W2m[cb2][lq<<3];
  b8v wl2=*(const b8v*)&W2l[cb2][lq<<3];
  for(int rt=0; rt<m; rt+=64){
    int rbase=rt+rt4*16;
    if(rbase<m){
      float oldv[4];
      #pragma unroll
      for(int i=0;i<4;i++) oldv[i]=S[k0+rbase+4*lq+i][cb2];
      b8v ah2,am3,al3;
      #pragma unroll
      for(int e=0;e<8;e++){
        size_t o2=(size_t)(8*lq+e)*m + rbase+lr;
        ah2[e]=vh[o2]; am3[e]=vm2[o2]; al3[e]=vl[o2];
      }
      f4v a2={0.f,0.f,0.f,0.f};
      a2=mfma6(ah2,am3,al3,wh,wm,wl2,a2);
      #pragma unroll
      for(int i=0;i<4;i++)
        S[k0+rbase+4*lq+i][cb2]=oldv[i]-a2[i];
    }
  }
  __syncthreads();
}

// ---------------- panel factor on LDS stripe (register p, S as broadcast) ---
template<int MQ>
__device__ __forceinline__ void panel_S(float (*S)[33], char* SC, int c0, int m,
    short* __restrict__ vh, short* __restrict__ vm2, short* __restrict__ vl,
    float* __restrict__ Tw){
  float (*Ssav)[33]=(float(*)[33])(SC);      // 4224
  float* taus=(float*)(SC+4224);             // 128
  int tid=threadIdx.x, c=tid>>4, rw=tid&15;
  int mq=m>>4;
  float p[MQ];
  #pragma unroll
  for(int q=0;q<MQ;q++){
    p[q]=0.f;
    if(q<mq) p[q]=S[c0+rw+(q<<4)][c];
  }
  __syncthreads();
  #pragma unroll 1
  for(int j=0;j<NB;j++){
    if(c==j){
      float ss=0.f, al=0.f;
      #pragma unroll
      for(int q=0;q<MQ;q++) if(q<mq){
        int r=rw+(q<<4);
        float pv=p[q];
        if(r>j) ss+=pv*pv; else if(r==j) al=pv;
      }
      #pragma unroll
      for(int o=8;o>0;o>>=1){ ss+=__shfl_xor(ss,o,16); al+=__shfl_xor(al,o,16); }
      float tau,scale;
      if(ss==0.f){ tau=0.f; scale=0.f; }
      else{
        double bn=sqrt((double)al*(double)al+(double)ss);
        float beta=(al>=0.f)?(float)(-bn):(float)bn;   // -sign(alpha)*norm
        tau=(beta-al)/beta; scale=1.f/(al-beta);
      }
      #pragma unroll
      for(int q=0;q<MQ;q++) if(q<mq){
        int r=rw+(q<<4);
        if(r>j){ p[q]*=scale; S[c0+r][j]=p[q]; }
        else if(r==j) S[c0+r][j]=1.f;
      }
      if(rw==0) taus[j]=tau;
    }
    __syncthreads();
    float tau=taus[j];
    float sc=0.f;
    #pragma unroll
    for(int q=0;q<MQ;q++) if(q<mq){
      int r=rw+(q<<4);
      if(r>=j) sc+=S[c0+r][j]*p[q];
    }
    #pragma unroll
    for(int o=8;o>0;o>>=1) sc+=__shfl_xor(sc,o,16);
    if(c>j){
      float wv=tau*sc;
      #pragma unroll
      for(int q=0;q<MQ;q++) if(q<mq){
        int r=rw+(q<<4);
        if(r>=j) p[q]-=wv*S[c0+r][j];
      }
    } else if(c<j && rw==0) Ssav[j][c]=sc;
  }
  __syncthreads();
  // T build (validated r9-r11; lane rw holds T[c][rw], T[c][rw+16])
  float tq0=0.f,tq1=0.f;
  #pragma unroll
  for(int jj=0;jj<32;jj++){
    float tj=taus[jj];
    float s=((rw<jj)?tq0*Ssav[jj][rw]:0.f)+((rw+16<jj)?tq1*Ssav[jj][rw+16]:0.f);
    #pragma unroll
    for(int o=8;o>0;o>>=1) s+=__shfl_xor(s,o,16);
    float val=-tj*s;
    if(jj>c){ if((jj&15)==rw){ if(jj<16) tq0=val; else tq1=val; } }
    else if(jj==c){ if((jj&15)==rw){ if(jj<16) tq0=tj; else tq1=tj; } }
  }
  Tw[(c<<5)+rw]=tq0;
  Tw[(c<<5)+rw+16]=tq1;
  // V^T writeback, pre-split 3-way
  #pragma unroll
  for(int q=0;q<MQ;q++) if(q<mq){
    int r=rw+(q<<4);
    float v=(r>c)?p[q]:((r==c)?1.f:0.f);
    short h,mi,lo; bsplit3(v,h,mi,lo);
    size_t o2=(size_t)c*m+r;
    vh[o2]=h; vm2[o2]=mi; vl[o2]=lo;
  }
  __syncthreads();
}

// ---------------- mega-kernel: whole 4-layer pipeline, stripe-resident ------
__global__ __launch_bounds__(512) void k_mega(const float* __restrict__ x0, float* __restrict__ out,
    const int* __restrict__ ei, const float* __restrict__ swv,
    const float* __restrict__ degF, const int* __restrict__ rowoff,
    short* vTh, short* vTm, short* vTl, float* Tws, int* flags){
  cg::grid_group grid = cg::this_grid();
  extern __shared__ char SMEM[];
  float (*S)[33]=(float(*)[33])SMEM;
  char* SC=SMEM+135168;
  int bid=blockIdx.x, tid=threadIdx.x;
  int b=bid>>5, j=bid&31, c0=j<<5;
  short* vhb=vTh+(size_t)b*VSTR;
  short* vmb=vTm+(size_t)b*VSTR;
  short* vlb=vTl+(size_t)b*VSTR;
  float* Tb=Tws+((size_t)b<<15);

  // load x0 stripe -> S, write slab 0 of out
  for(int idx=tid; idx<NN*32; idx+=512){
    int r=idx>>5, cc=idx&31;
    float v=x0[(((size_t)b*NN+r)<<10)+c0+cc];
    S[r][cc]=v;
    out[((size_t)b*NN+r)*OUTD + c0+cc]=v;
  }
  __syncthreads();

  for(int l=0;l<LL;l++){
    int* fl=flags+((l*BB+b)<<5);
    // conv: S (prev Q / x0) -> A, in LDS
    conv_S(S,ei,swv,degF,rowoff);
    // geqrf: flag-gated applies, then own panel
    for(int kb=0;kb<j;kb++){
      wait_flag(&fl[kb]);
      size_t vo=voff(kb);
      apply_S<true>(S,SC,vhb+vo,vmb+vo,vlb+vo,Tb+((size_t)kb<<10),kb<<5);
    }
    {
      int m=NN-c0;
      size_t vo=voff(j);
      float* Tw=Tb+((size_t)j<<10);
      if(j<8)       panel_S<64>(S,SC,c0,m,vhb+vo,vmb+vo,vlb+vo,Tw);
      else if(j<16) panel_S<48>(S,SC,c0,m,vhb+vo,vmb+vo,vlb+vo,Tw);
      else if(j<24) panel_S<32>(S,SC,c0,m,vhb+vo,vmb+vo,vlb+vo,Tw);
      else          panel_S<16>(S,SC,c0,m,vhb+vo,vmb+vo,vlb+vo,Tw);
      set_flag(&fl[j]);
    }
    // orgqr: S <- E_j, descending applies (V/T all published)
    for(int idx=tid; idx<NN*32; idx+=512){
      int r=idx>>5, cc=idx&31;
      S[r][cc]=(r==c0+cc)?1.f:0.f;
    }
    __syncthreads();
    for(int kb=j;kb>=0;kb--){
      size_t vo=voff(kb);
      apply_S<false>(S,SC,vhb+vo,vmb+vo,vlb+vo,Tb+((size_t)kb<<10),kb<<5);
    }
    // write Q -> out slab l+1
    for(int idx=tid; idx<NN*32; idx+=512){
      int r=idx>>5, cc=idx&31;
      out[((size_t)b*NN+r)*OUTD+(size_t)(l+1)*1024 + c0+cc]=S[r][cc];
    }
    grid.sync();   // V/T slot reuse safety across layers
  }
}

extern "C" void kernel_launch(void* const* d_in, const int* in_sizes, int n_in,
                              void* d_out, int out_size, void* d_ws, size_t ws_size,
                              hipStream_t stream){
  const float* x0=(const float*)d_in[0];
  const int* ei=(const int*)d_in[1];
  int E=in_sizes[1]/2;
  float* out=(float*)d_out;
  // ws layout (~27.1 MB)
  float* W=(float*)d_ws;
  float* degF=W;                          // 1024
  float* isq =W+1024;                     // 1024
  int*  rowoff=(int*)(W+2048);            // 1025 (pad to 1040)
  int*  flags =(int*)(W+2048)+1040;       // 1024
  float* swv  =W+4352;                    // E (<=16384)
  float* Tws  =W+20736;                   // 8*32*1024 = 262144
  short* vTh  =(short*)(W+282880);        // 8*VSTR shorts each
  short* vTm  =vTh+(size_t)BB*VSTR;
  short* vTl  =vTm+(size_t)BB*VSTR;

  (void)hipFuncSetAttribute(reinterpret_cast<const void*>(&k_mega),
                            hipFuncAttributeMaxDynamicSharedMemorySize, SMBYTES);

  k_init<<<1,1024,0,stream>>>(degF,flags);
  k_deg<<<(E+255)/256,256,0,stream>>>(ei,degF,E);
  k_scan<<<1,NN,0,stream>>>(degF,isq,rowoff);
  k_sw<<<(E+255)/256,256,0,stream>>>(ei,isq,swv,E);

  void* kargs[]={(void*)&x0,(void*)&out,(void*)&ei,(void*)&swv,(void*)&degF,
                 (void*)&rowoff,(void*)&vTh,(void*)&vTm,(void*)&vTl,(void*)&Tws,(void*)&flags};
  hipLaunchCooperativeKernel(reinterpret_cast<void*>(k_mega),
                             dim3(256),dim3(512),kargs,SMBYTES,stream);
}

// Round 13
// 13028.490 us; speedup vs baseline: 6.6810x; 1.1382x over previous
//
#include <hip/hip_runtime.h>
#include <hip/hip_cooperative_groups.h>
#include <cmath>

namespace cg = cooperative_groups;

#define NN 1024
#define BB 8
#define LL 4
#define OUTD 5120
#define NB 32
#define VSTR 540672ull     // per-batch elements of V^T dump (sum of 32*m_i)
#define SMBYTES 152064     // 1024*33*4 (stripe) + 16896 (scratch)

typedef short b8v __attribute__((ext_vector_type(8)));
typedef short s4v __attribute__((ext_vector_type(4)));
typedef float f4v __attribute__((ext_vector_type(4)));
typedef float f4  __attribute__((ext_vector_type(4)));

__device__ __forceinline__ unsigned short f2bf(float x){
  unsigned u=__float_as_uint(x);
  return (unsigned short)((u + 0x7FFFu + ((u>>16)&1u))>>16);
}
__device__ __forceinline__ float bf2f(unsigned short h){
  return __uint_as_float(((unsigned)h)<<16);
}
// 3-split: x=h+m+l -> 6-product MFMA == fp32-equivalent (validated r5-r12)
__device__ __forceinline__ void bsplit3(float x, short& h, short& m, short& l){
  unsigned short hh=f2bf(x);
  float r1=x-bf2f(hh);
  unsigned short mm=f2bf(r1);
  float r2=r1-bf2f(mm);
  h=(short)hh; m=(short)mm; l=(short)f2bf(r2);
}
__device__ __forceinline__ f4v mfma6(b8v ah,b8v am,b8v al,b8v bh,b8v bm,b8v bl,f4v acc){
  acc=__builtin_amdgcn_mfma_f32_16x16x32_bf16(al,bh,acc,0,0,0);
  acc=__builtin_amdgcn_mfma_f32_16x16x32_bf16(ah,bl,acc,0,0,0);
  acc=__builtin_amdgcn_mfma_f32_16x16x32_bf16(am,bm,acc,0,0,0);
  acc=__builtin_amdgcn_mfma_f32_16x16x32_bf16(am,bh,acc,0,0,0);
  acc=__builtin_amdgcn_mfma_f32_16x16x32_bf16(ah,bm,acc,0,0,0);
  acc=__builtin_amdgcn_mfma_f32_16x16x32_bf16(ah,bh,acc,0,0,0);
  return acc;
}
__device__ __forceinline__ size_t voff(int kb){
  return 32768ull*(size_t)kb - 512ull*(size_t)kb*(size_t)(kb-1);
}

// ---- flags (protocol validated r10-r12) ----
__device__ __forceinline__ void wait_flag(int* f){
  if(threadIdx.x==0){
    while(__hip_atomic_load(f, __ATOMIC_RELAXED, __HIP_MEMORY_SCOPE_AGENT)==0)
      __builtin_amdgcn_s_sleep(8);
    __threadfence();
  }
  __syncthreads();
}
__device__ __forceinline__ void set_flag(int* f){
  __syncthreads();
  if(threadIdx.x==0)
    __hip_atomic_store(f, 1, __ATOMIC_RELEASE, __HIP_MEMORY_SCOPE_AGENT);
}

// ---------------- setup ----------------
__global__ void k_init(float* degF, int* flags){
  degF[threadIdx.x]=0.f;
  flags[threadIdx.x]=0;     // LL*BB*32 = 1024
}
__global__ void k_deg(const int* __restrict__ ei, float* __restrict__ degF, int E){
  int e=blockIdx.x*blockDim.x+threadIdx.x;
  if(e<E) atomicAdd(&degF[ei[2*e]],1.f);
}
__global__ void k_scan(const float* __restrict__ degF, float* __restrict__ isq, int* __restrict__ rowoff){
  __shared__ int s[NN];
  int i=threadIdx.x;
  int d=(int)degF[i];
  s[i]=d; __syncthreads();
  for(int off=1;off<NN;off<<=1){
    int v=(i>=off)?s[i-off]:0;
    __syncthreads();
    s[i]+=v;
    __syncthreads();
  }
  if(i==0) rowoff[0]=0;
  rowoff[i+1]=s[i];
  isq[i]=(d>0)?(float)(1.0/sqrt((double)d)):0.f;
}
__global__ void k_sw(const int* __restrict__ ei, const float* __restrict__ isq,
                     float* __restrict__ swv, int E){
  int e=blockIdx.x*blockDim.x+threadIdx.x;
  if(e<E) swv[e]=isq[ei[2*e]]*isq[ei[2*e+1]];
}

// ---------------- conv on LDS-resident stripe (r12-verbatim) ----------------
__device__ void conv_S(float (*S)[33], const int* __restrict__ ei,
                       const float* __restrict__ swv, const float* __restrict__ degF,
                       const int* __restrict__ rowoff){
  int tid=threadIdx.x;
  int ra=2*tid, rb2=2*tid+1;
  int e0=rowoff[ra], e1=rowoff[rb2], e2=rowoff[rb2+1];
  float a0[32], a1[32];
  #pragma unroll
  for(int c=0;c<32;c++){ a0[c]=0.f; a1[c]=0.f; }
  for(int e=e0;e<e1;e++){
    int dv=ei[2*e+1]; float w=swv[e];
    #pragma unroll
    for(int c=0;c<32;c++) a0[c]+=w*S[dv][c];
  }
  for(int e=e1;e<e2;e++){
    int dv=ei[2*e+1]; float w=swv[e];
    #pragma unroll
    for(int c=0;c<32;c++) a1[c]+=w*S[dv][c];
  }
  float d0=degF[ra], d1=degF[rb2];
  float cm0=(float)(e1-e0)*d0/fmaxf(d0,1.f);
  float cm1=(float)(e2-e1)*d1/fmaxf(d1,1.f);
  #pragma unroll
  for(int c=0;c<32;c++){
    a0[c]=0.5f*a0[c]+0.5f*cm0*S[ra][c];
    a1[c]=0.5f*a1[c]+0.5f*cm1*S[rb2][c];
  }
  __syncthreads();
  #pragma unroll
  for(int c=0;c<32;c++){ S[ra][c]=a0[c]; S[rb2][c]=a1[c]; }
  __syncthreads();
}

// ---------------- block reflector apply on LDS stripe (r12-verbatim) --------
template<bool TRANS>
__device__ void apply_S(float (*S)[33], char* SC,
    const short* __restrict__ vh, const short* __restrict__ vm2, const short* __restrict__ vl,
    const float* __restrict__ Tb, int k0){
  float (*Tsh)[33]=(float(*)[33])(SC);              // 4224
  float (*Wt)[33] =(float(*)[33])(SC+4224);         // 4224
  float (*Wp)[32][33]=(float(*)[32][33])(SC+8448);  // 8448
  short (*W2h)[40]=(short(*)[40])(SC+8448);         // aliases Wp (dead by then)
  short (*W2m)[40]=(short(*)[40])(SC+11008);
  short (*W2l)[40]=(short(*)[40])(SC+13568);
  int tid=threadIdx.x, w=tid>>6, lane=tid&63, lr=lane&15, lq=lane>>4;
  int m=NN-k0;
  for(int idx=tid; idx<1024; idx+=512) Tsh[idx>>5][idx&31]=Tb[idx];
  // ---- pass 1: W = V^T * S (K=m) ----
  int jt=w&1, ct=(w>>1)&1, kh=w>>2;
  int ja=jt*16+lr, cb=ct*16+lr;
  int ko=(kh<<5)+(lq<<3);
  const short* ph=vh +(size_t)ja*m;
  const short* pm=vm2+(size_t)ja*m;
  const short* pl=vl +(size_t)ja*m;
  f4v acc={0.f,0.f,0.f,0.f};
  const b8v zz={0,0,0,0,0,0,0,0};
  b8v ah=zz,amv=zz,alv=zz;
  if(ko<m){ ah=*(const b8v*)(ph+ko); amv=*(const b8v*)(pm+ko); alv=*(const b8v*)(pl+ko); }
  for(int rt=0; rt<m; rt+=64){
    int kk=rt+ko;
    b8v nh=zz,nm=zz,nl=zz;
    int nk=kk+64;
    if(nk<m){ nh=*(const b8v*)(ph+nk); nm=*(const b8v*)(pm+nk); nl=*(const b8v*)(pl+nk); }
    float sv[8];
    if(kk<m){
      #pragma unroll
      for(int e=0;e<8;e++) sv[e]=S[k0+kk+e][cb];
    } else {
      #pragma unroll
      for(int e=0;e<8;e++) sv[e]=0.f;
    }
    b8v bh,bm2,bl2;
    #pragma unroll
    for(int e=0;e<8;e++){ short h,mi,lo; bsplit3(sv[e],h,mi,lo); bh[e]=h; bm2[e]=mi; bl2[e]=lo; }
    acc=mfma6(ah,amv,alv,bh,bm2,bl2,acc);
    ah=nh; amv=nm; alv=nl;
  }
  // C/D layout: col=lane&15, row=4*(lane>>4)+i [verified m89]
  #pragma unroll
  for(int i=0;i<4;i++) Wp[kh][jt*16+4*lq+i][ct*16+lr]=acc[i];
  __syncthreads();
  #pragma unroll
  for(int s=0;s<2;s++){
    int idx=tid+(s<<9), j=idx>>5, cc=idx&31;
    Wt[j][cc]=Wp[0][j][cc]+Wp[1][j][cc];
  }
  __syncthreads();
  // ---- T apply (f32) ----
  float w2r[2];
  #pragma unroll
  for(int s=0;s<2;s++){
    int idx=tid+(s<<9), cc=idx>>5, j=idx&31;
    float s2=0.f;
    if(TRANS){ for(int q=0;q<=j;q++) s2+=Tsh[q][j]*Wt[q][cc]; }
    else     { for(int q=j;q<32;q++) s2+=Tsh[j][q]*Wt[q][cc]; }
    w2r[s]=s2;
  }
  __syncthreads();
  #pragma unroll
  for(int s=0;s<2;s++){
    int idx=tid+(s<<9), cc=idx>>5, j=idx&31;
    short h,mi,lo; bsplit3(w2r[s],h,mi,lo);
    W2h[cc][j]=h; W2m[cc][j]=mi; W2l[cc][j]=lo;
  }
  __syncthreads();
  // ---- pass 2: S -= V * W2 (K=32) ----
  int rt4=w&3, ct2=w>>2;
  int cb2=ct2*16+lr;
  b8v wh=*(const b8v*)&W2h[cb2][lq<<3];
  b8v wm=*(const b8v*)&W2m[cb2][lq<<3];
  b8v wl2=*(const b8v*)&W2l[cb2][lq<<3];
  for(int rt=0; rt<m; rt+=64){
    int rbase=rt+rt4*16;
    if(rbase<m){
      float oldv[4];
      #pragma unroll
      for(int i=0;i<4;i++) oldv[i]=S[k0+rbase+4*lq+i][cb2];
      b8v ah2,am3,al3;
      #pragma unroll
      for(int e=0;e<8;e++){
        size_t o2=(size_t)(8*lq+e)*m + rbase+lr;
        ah2[e]=vh[o2]; am3[e]=vm2[o2]; al3[e]=vl[o2];
      }
      f4v a2={0.f,0.f,0.f,0.f};
      a2=mfma6(ah2,am3,al3,wh,wm,wl2,a2);
      #pragma unroll
      for(int i=0;i<4;i++)
        S[k0+rbase+4*lq+i][cb2]=oldv[i]-a2[i];
    }
  }
  __syncthreads();
}

// ---------------- panel factor: float4 row-chunks, b128 v-broadcast ---------
// Thread (c=tid>>4, rw=tid&15) owns rows r = 4rw + 64q + i (i=0..3, q<NQ).
// v broadcast via dense double-buffered vb (16B-aligned -> ds_read/write_b128).
// Chunk (rw,q) valid iff 4rw+64q < m (m multiple of 32 => all-or-nothing).
template<int NQ>
__device__ __forceinline__ void panel_S(float (*S)[33], char* SC, int c0, int m,
    short* __restrict__ vh, short* __restrict__ vm2, short* __restrict__ vl,
    float* __restrict__ Tw){
  float* vb2=(float*)SC;                     // 2*1024 f32 double buffer
  float (*Ssav)[33]=(float(*)[33])(SC+8192); // larft dot vectors
  float* taus=(float*)(SC+12416);            // 32
  int tid=threadIdx.x, c=tid>>4, rw=tid&15;
  int rb=rw<<2;
  f4 p4[NQ];
  #pragma unroll
  for(int q=0;q<NQ;q++){
    #pragma unroll
    for(int i=0;i<4;i++){
      int r=rb+(q<<6)+i;
      p4[q][i]=(rb+(q<<6)<m)? S[c0+r][c] : 0.f;
    }
  }
  __syncthreads();
  #pragma unroll 1
  for(int j=0;j<NB;j++){
    float* vb=vb2+((j&1)<<10);
    if(c==j){
      float ss=0.f, al=0.f;
      #pragma unroll
      for(int q=0;q<NQ;q++) if(rb+(q<<6)<m){
        #pragma unroll
        for(int i=0;i<4;i++){
          int r=rb+(q<<6)+i;
          float pv=p4[q][i];
          if(r>j) ss+=pv*pv; else if(r==j) al=pv;
        }
      }
      #pragma unroll
      for(int o=8;o>0;o>>=1){ ss+=__shfl_xor(ss,o,16); al+=__shfl_xor(al,o,16); }
      float tau,scale;
      if(ss==0.f){ tau=0.f; scale=0.f; }
      else{
        double bn=sqrt((double)al*(double)al+(double)ss);
        float beta=(al>=0.f)?(float)(-bn):(float)bn;   // -sign(alpha)*norm
        tau=(beta-al)/beta; scale=1.f/(al-beta);
      }
      // scale own column, publish v (v[r<j]=0 encodes the r>=j mask)
      #pragma unroll
      for(int q=0;q<NQ;q++) if(rb+(q<<6)<m){
        f4 v4;
        #pragma unroll
        for(int i=0;i<4;i++){
          int r=rb+(q<<6)+i;
          float pv=p4[q][i];
          if(r>j){ pv*=scale; p4[q][i]=pv; v4[i]=pv; }
          else v4[i]=(r==j)?1.f:0.f;
        }
        *(f4*)&vb[rb+(q<<6)]=v4;
      }
      if(rw==0) taus[j]=tau;
    }
    __syncthreads();
    float tau=taus[j];
    // dot: sc = v . p  (v zero-masked below j)
    float sc=0.f;
    #pragma unroll
    for(int q=0;q<NQ;q++) if(rb+(q<<6)<m){
      f4 v4=*(const f4*)&vb[rb+(q<<6)];
      #pragma unroll
      for(int i=0;i<4;i++) sc+=v4[i]*p4[q][i];
    }
    #pragma unroll
    for(int o=8;o>0;o>>=1) sc+=__shfl_xor(sc,o,16);
    if(c>j){
      float wv=tau*sc;
      #pragma unroll
      for(int q=0;q<NQ;q++) if(rb+(q<<6)<m){
        f4 v4=*(const f4*)&vb[rb+(q<<6)];
        #pragma unroll
        for(int i=0;i<4;i++) p4[q][i]-=wv*v4[i];
      }
    } else if(c<j && rw==0) Ssav[j][c]=sc;
  }
  __syncthreads();
  // T build (validated r9-r12; lane rw holds T[c][rw], T[c][rw+16])
  float tq0=0.f,tq1=0.f;
  #pragma unroll
  for(int jj=0;jj<32;jj++){
    float tj=taus[jj];
    float s=((rw<jj)?tq0*Ssav[jj][rw]:0.f)+((rw+16<jj)?tq1*Ssav[jj][rw+16]:0.f);
    #pragma unroll
    for(int o=8;o>0;o>>=1) s+=__shfl_xor(s,o,16);
    float val=-tj*s;
    if(jj>c){ if((jj&15)==rw){ if(jj<16) tq0=val; else tq1=val; } }
    else if(jj==c){ if((jj&15)==rw){ if(jj<16) tq0=tj; else tq1=tj; } }
  }
  Tw[(c<<5)+rw]=tq0;
  Tw[(c<<5)+rw+16]=tq1;
  // V^T writeback, pre-split 3-way, short4 stores
  #pragma unroll
  for(int q=0;q<NQ;q++) if(rb+(q<<6)<m){
    s4v h4,m4,l4;
    #pragma unroll
    for(int i=0;i<4;i++){
      int r=rb+(q<<6)+i;
      float v=(r>c)?p4[q][i]:((r==c)?1.f:0.f);
      short hh,mi,lo; bsplit3(v,hh,mi,lo);
      h4[i]=hh; m4[i]=mi; l4[i]=lo;
    }
    size_t o2=(size_t)c*m + rb+(q<<6);
    *(s4v*)&vh[o2]=h4; *(s4v*)&vm2[o2]=m4; *(s4v*)&vl[o2]=l4;
  }
  __syncthreads();
}

// ---------------- mega-kernel: whole 4-layer pipeline, stripe-resident ------
__global__ __launch_bounds__(512) void k_mega(const float* __restrict__ x0, float* __restrict__ out,
    const int* __restrict__ ei, const float* __restrict__ swv,
    const float* __restrict__ degF, const int* __restrict__ rowoff,
    short* vTh, short* vTm, short* vTl, float* Tws, int* flags){
  cg::grid_group grid = cg::this_grid();
  extern __shared__ char SMEM[];
  float (*S)[33]=(float(*)[33])SMEM;
  char* SC=SMEM+135168;
  int bid=blockIdx.x, tid=threadIdx.x;
  int b=bid>>5, j=bid&31, c0=j<<5;
  short* vhb=vTh+(size_t)b*VSTR;
  short* vmb=vTm+(size_t)b*VSTR;
  short* vlb=vTl+(size_t)b*VSTR;
  float* Tb=Tws+((size_t)b<<15);

  // load x0 stripe -> S, write slab 0 of out
  for(int idx=tid; idx<NN*32; idx+=512){
    int r=idx>>5, cc=idx&31;
    float v=x0[(((size_t)b*NN+r)<<10)+c0+cc];
    S[r][cc]=v;
    out[((size_t)b*NN+r)*OUTD + c0+cc]=v;
  }
  __syncthreads();

  for(int l=0;l<LL;l++){
    int* fl=flags+((l*BB+b)<<5);
    // conv: S (prev Q / x0) -> A, in LDS
    conv_S(S,ei,swv,degF,rowoff);
    // geqrf: flag-gated applies, then own panel
    for(int kb=0;kb<j;kb++){
      wait_flag(&fl[kb]);
      size_t vo=voff(kb);
      apply_S<true>(S,SC,vhb+vo,vmb+vo,vlb+vo,Tb+((size_t)kb<<10),kb<<5);
    }
    {
      int m=NN-c0;
      size_t vo=voff(j);
      float* Tw=Tb+((size_t)j<<10);
      if(j<8)       panel_S<16>(S,SC,c0,m,vhb+vo,vmb+vo,vlb+vo,Tw);
      else if(j<16) panel_S<12>(S,SC,c0,m,vhb+vo,vmb+vo,vlb+vo,Tw);
      else if(j<24) panel_S<8 >(S,SC,c0,m,vhb+vo,vmb+vo,vlb+vo,Tw);
      else          panel_S<4 >(S,SC,c0,m,vhb+vo,vmb+vo,vlb+vo,Tw);
      set_flag(&fl[j]);
    }
    // orgqr: S <- E_j, descending applies (V/T all published)
    for(int idx=tid; idx<NN*32; idx+=512){
      int r=idx>>5, cc=idx&31;
      S[r][cc]=(r==c0+cc)?1.f:0.f;
    }
    __syncthreads();
    for(int kb=j;kb>=0;kb--){
      size_t vo=voff(kb);
      apply_S<false>(S,SC,vhb+vo,vmb+vo,vlb+vo,Tb+((size_t)kb<<10),kb<<5);
    }
    // write Q -> out slab l+1
    for(int idx=tid; idx<NN*32; idx+=512){
      int r=idx>>5, cc=idx&31;
      out[((size_t)b*NN+r)*OUTD+(size_t)(l+1)*1024 + c0+cc]=S[r][cc];
    }
    grid.sync();   // V/T slot reuse safety across layers
  }
}

extern "C" void kernel_launch(void* const* d_in, const int* in_sizes, int n_in,
                              void* d_out, int out_size, void* d_ws, size_t ws_size,
                              hipStream_t stream){
  const float* x0=(const float*)d_in[0];
  const int* ei=(const int*)d_in[1];
  int E=in_sizes[1]/2;
  float* out=(float*)d_out;
  // ws layout (~27.1 MB)
  float* W=(float*)d_ws;
  float* degF=W;                          // 1024
  float* isq =W+1024;                     // 1024
  int*  rowoff=(int*)(W+2048);            // 1025 (pad to 1040)
  int*  flags =(int*)(W+2048)+1040;       // 1024
  float* swv  =W+4352;                    // E (<=16384)
  float* Tws  =W+20736;                   // 8*32*1024 = 262144
  short* vTh  =(short*)(W+282880);        // 8*VSTR shorts each
  short* vTm  =vTh+(size_t)BB*VSTR;
  short* vTl  =vTm+(size_t)BB*VSTR;

  (void)hipFuncSetAttribute(reinterpret_cast<const void*>(&k_mega),
                            hipFuncAttributeMaxDynamicSharedMemorySize, SMBYTES);

  k_init<<<1,1024,0,stream>>>(degF,flags);
  k_deg<<<(E+255)/256,256,0,stream>>>(ei,degF,E);
  k_scan<<<1,NN,0,stream>>>(degF,isq,rowoff);
  k_sw<<<(E+255)/256,256,0,stream>>>(ei,isq,swv,E);

  void* kargs[]={(void*)&x0,(void*)&out,(void*)&ei,(void*)&swv,(void*)&degF,
                 (void*)&rowoff,(void*)&vTh,(void*)&vTm,(void*)&vTl,(void*)&Tws,(void*)&flags};
  hipLaunchCooperativeKernel(reinterpret_cast<void*>(k_mega),
                             dim3(256),dim3(512),kargs,SMBYTES,stream);
}